// Round 8
// baseline (229.903 us; speedup 1.0000x reference)
//
#include <hip/hip_runtime.h>
#include <stdint.h>

#define C_DIM 512
#define NHEADS 8
#define HDIM 64
#define BATCH 8
#define NPIX 1024
// Q pre-scale: (1/sqrt(64)) * log2(e) -> exp becomes bare exp2
#define Q_PRESCALE 0.18033688011112042f

typedef __bf16 bf16x8 __attribute__((ext_vector_type(8)));
typedef float f32x4 __attribute__((ext_vector_type(4)));
typedef float f32x16 __attribute__((ext_vector_type(16)));

__device__ __forceinline__ unsigned short f2bf(float f) {
  union { float f; unsigned u; } v; v.f = f;
  unsigned r = v.u + 0x7fffu + ((v.u >> 16) & 1u);
  return (unsigned short)(r >> 16);
}

__device__ __forceinline__ void gl_lds16(const void* g, void* l) {
  __builtin_amdgcn_global_load_lds(
      (__attribute__((address_space(1))) void*)g,
      (__attribute__((address_space(3))) void*)l,
      16, 0, 0);
}

// ---------------- weights f32 -> bf16 ----------------
__global__ __launch_bounds__(256) void k_prep(const float* __restrict__ wq,
                                              const float* __restrict__ wk,
                                              const float* __restrict__ wv,
                                              const float* __restrict__ wp,
                                              unsigned short* __restrict__ wbf) {
  const int n = C_DIM * C_DIM;
  for (int i = blockIdx.x * blockDim.x + threadIdx.x; i < 4 * n;
       i += gridDim.x * blockDim.x) {
    const float* src = (i < n) ? wq : (i < 2 * n) ? wk : (i < 3 * n) ? wv : wp;
    wbf[i] = f2bf(src[i & (n - 1)]);
  }
}

// ---------------- BN (eval) + transpose: x (B,C,N) f32 -> hbT (B,N,C) bf16 ----
__global__ __launch_bounds__(256) void k_bnT(const float* __restrict__ x,
                                             const float* __restrict__ gamma,
                                             const float* __restrict__ beta,
                                             const float* __restrict__ rmean,
                                             const float* __restrict__ rvar,
                                             unsigned short* __restrict__ hbT) {
  __shared__ unsigned short tile[64][72];
  const int b = blockIdx.z, c0 = blockIdx.y * 64, n0 = blockIdx.x * 64;
  const int t = threadIdx.x;
#pragma unroll
  for (int it = 0; it < 4; ++it) {
    int c = it * 16 + (t >> 4);
    int n = (t & 15) * 4;
    const float4 v = *(const float4*)&x[((size_t)b * C_DIM + c0 + c) * NPIX + n0 + n];
    int cc = c0 + c;
    float inv = gamma[cc] * rsqrtf(rvar[cc] + 1e-5f);
    float add = beta[cc] - rmean[cc] * inv;
    tile[c][n + 0] = f2bf(v.x * inv + add);
    tile[c][n + 1] = f2bf(v.y * inv + add);
    tile[c][n + 2] = f2bf(v.z * inv + add);
    tile[c][n + 3] = f2bf(v.w * inv + add);
  }
  __syncthreads();
#pragma unroll
  for (int it = 0; it < 2; ++it) {
    int n = it * 32 + (t >> 3);
    int cj = (t & 7) * 8;
    unsigned short tmp[8];
#pragma unroll
    for (int u = 0; u < 8; ++u) tmp[u] = tile[cj + u][n];
    uint4 pk;
    pk.x = (unsigned)tmp[0] | ((unsigned)tmp[1] << 16);
    pk.y = (unsigned)tmp[2] | ((unsigned)tmp[3] << 16);
    pk.z = (unsigned)tmp[4] | ((unsigned)tmp[5] << 16);
    pk.w = (unsigned)tmp[6] | ((unsigned)tmp[7] << 16);
    *(uint4*)&hbT[((size_t)b * NPIX + n0 + n) * C_DIM + c0 + cj] = pk;
  }
}

// ---------------- QKV GEMM: OUT[o][n] = W h + b  (BK=64, 8 K-steps) --------
// Q,K stored transposed (B,N,C); V stored (B,C,N). Q pre-scaled by Q_PRESCALE.
__global__ __launch_bounds__(256) void k_qkv(const unsigned short* __restrict__ wbf,
                                             const float* __restrict__ bq,
                                             const float* __restrict__ bk,
                                             const float* __restrict__ bv,
                                             const unsigned short* __restrict__ hbT,
                                             unsigned short* __restrict__ QT,
                                             unsigned short* __restrict__ KT,
                                             unsigned short* __restrict__ Vb) {
  __shared__ unsigned short Atile[128 * 64];
  __shared__ unsigned short Btile[128 * 64];
  const int which = blockIdx.z >> 3;
  const int b = blockIdx.z & 7;
  const int m0 = blockIdx.y * 128, n0 = blockIdx.x * 128;
  const unsigned short* W = wbf + (size_t)which * C_DIM * C_DIM;
  const int t = threadIdx.x, wave = t >> 6, lane = t & 63;
  const int wr = wave >> 1, wc = wave & 1;
  f32x4 acc[4][4] = {};

  for (int k0 = 0; k0 < C_DIM; k0 += 64) {
    __syncthreads();
#pragma unroll
    for (int s = 0; s < 4; ++s) {
      int row = s * 32 + wave * 8 + (lane >> 3);
      int srcc = ((lane & 7) ^ (row & 7)) * 8;
      gl_lds16(&W[(size_t)(m0 + row) * C_DIM + k0 + srcc],
               &Atile[(s * 32 + wave * 8) * 64]);
      gl_lds16(&hbT[((size_t)b * NPIX + n0 + row) * C_DIM + k0 + srcc],
               &Btile[(s * 32 + wave * 8) * 64]);
    }
    __syncthreads();
#pragma unroll
    for (int ks2 = 0; ks2 < 2; ++ks2) {
      bf16x8 af[4], bfr[4];
#pragma unroll
      for (int i = 0; i < 4; ++i) {
        int row = wr * 64 + i * 16 + (lane & 15);
        int phys = (ks2 * 4 + (lane >> 4)) ^ (row & 7);
        af[i] = *(const bf16x8*)&Atile[row * 64 + phys * 8];
      }
#pragma unroll
      for (int j = 0; j < 4; ++j) {
        int row = wc * 64 + j * 16 + (lane & 15);
        int phys = (ks2 * 4 + (lane >> 4)) ^ (row & 7);
        bfr[j] = *(const bf16x8*)&Btile[row * 64 + phys * 8];
      }
#pragma unroll
      for (int i = 0; i < 4; ++i)
#pragma unroll
        for (int j = 0; j < 4; ++j)
          acc[i][j] = __builtin_amdgcn_mfma_f32_16x16x32_bf16(af[i], bfr[j], acc[i][j], 0, 0, 0);
    }
  }

  const float* bias = (which == 0) ? bq : (which == 1) ? bk : bv;
  if (which < 2) {
    unsigned short* T = (which == 0) ? QT : KT;
    const float qs = (which == 0) ? Q_PRESCALE : 1.0f;
#pragma unroll
    for (int i = 0; i < 4; ++i) {
      int o = m0 + wr * 64 + i * 16 + (lane >> 4) * 4;
      float b0 = bias[o + 0], b1 = bias[o + 1], b2 = bias[o + 2], b3 = bias[o + 3];
#pragma unroll
      for (int j = 0; j < 4; ++j) {
        int n = n0 + wc * 64 + j * 16 + (lane & 15);
        ushort4 pk;
        pk.x = f2bf((acc[i][j][0] + b0) * qs);
        pk.y = f2bf((acc[i][j][1] + b1) * qs);
        pk.z = f2bf((acc[i][j][2] + b2) * qs);
        pk.w = f2bf((acc[i][j][3] + b3) * qs);
        *(ushort4*)&T[((size_t)b * NPIX + n) * C_DIM + o] = pk;
      }
    }
  } else {
#pragma unroll
    for (int i = 0; i < 4; ++i) {
      int o = m0 + wr * 64 + i * 16 + (lane >> 4) * 4;
#pragma unroll
      for (int j = 0; j < 4; ++j) {
        int n = n0 + wc * 64 + j * 16 + (lane & 15);
#pragma unroll
        for (int r = 0; r < 4; ++r)
          Vb[((size_t)b * C_DIM + o + r) * NPIX + n] = f2bf(acc[i][j][r] + bias[o + r]);
      }
    }
  }
}

// ---------------- attention v6: TLP-max — split-K x4, single buffer --------
// Grid 2048: b=bid&7, h=(bid>>3)&7, qt=(bid>>6)&7, ks=bid>>9 (0..3).
// Each block: 128 q x 256 kpix (4 tiles of 64). Single 16.5KB LDS buffer,
// stage->sync->compute->sync (TLP hides the stalls: target 6-7 waves/SIMD).
// VALU rowsum on S-layout (lane-aligned per q), no ones-MFMA (-20 VGPR).
__global__ __launch_bounds__(256, 6) void k_attn(const unsigned short* __restrict__ QT,
                                                 const unsigned short* __restrict__ KT,
                                                 const unsigned short* __restrict__ Vb,
                                                 unsigned short* __restrict__ Opart,
                                                 float* __restrict__ rs) {
  __shared__ unsigned short Ks[64 * 64];  // [kpix][c], chunk ^= (row&7)
  __shared__ unsigned short Vs[64 * 64];  // [d][kpix], chunk ^= (d&7)
  __shared__ float rs_lds[128];

  const int bid = blockIdx.x;
  const int b = bid & 7, h = (bid >> 3) & 7, qt = (bid >> 6) & 7, ks = bid >> 9;
  const int n0 = qt * 128;
  const int kbase0 = ks * 256;
  const int lane = threadIdx.x & 63, wave = threadIdx.x >> 6;
  const int l31 = lane & 31, hi = lane >> 5;

  // Q fragments (B-operand: col q = l31, k = c = kk*16 + hi*8 + j)
  bf16x8 qf[4];
  {
    const unsigned short* qbase =
        QT + ((size_t)b * NPIX + n0 + wave * 32 + l31) * C_DIM + h * HDIM + hi * 8;
#pragma unroll
    for (int kk = 0; kk < 4; ++kk) qf[kk] = *(const bf16x8*)(qbase + kk * 16);
  }

  f32x16 oacc[2] = {};
  float rs0 = 0.f, rs1 = 0.f;

  for (int tile = 0; tile < 4; ++tile) {
    const int m0 = kbase0 + tile * 64;
#pragma unroll
    for (int it = 0; it < 2; ++it) {
      int rb = it * 32 + wave * 8;
      int row = rb + (lane >> 3);
      int srcc = ((lane & 7) ^ (row & 7)) * 8;
      gl_lds16(&KT[((size_t)b * NPIX + m0 + row) * C_DIM + h * HDIM + srcc],
               &Ks[rb * 64]);
      gl_lds16(&Vb[((size_t)b * C_DIM + h * HDIM + row) * NPIX + m0 + srcc],
               &Vs[rb * 64]);
    }
    __syncthreads();

#pragma unroll
    for (int kt = 0; kt < 2; ++kt) {
      // S^T 32x32: A = K [32 kpix x 16 c], B = Q. Lane holds col q=l31.
      f32x16 s = {};
#pragma unroll
      for (int kk = 0; kk < 4; ++kk) {
        int row = kt * 32 + l31;
        int phys = (kk * 2 + hi) ^ (row & 7);
        bf16x8 kf = *(const bf16x8*)&Ks[row * 64 + phys * 8];
        s = __builtin_amdgcn_mfma_f32_32x32x16_bf16(kf, qf[kk], s, 0, 0, 0);
      }
      // P = 2^s (clip-free); rowsum per-lane (q=l31 aligned); pack bf16.
      unsigned w[8];
#pragma unroll
      for (int r2 = 0; r2 < 8; ++r2) {
        float e0 = exp2f(s[2 * r2]);
        float e1 = exp2f(s[2 * r2 + 1]);
        rs0 += e0;
        rs1 += e1;
        asm("v_cvt_pk_bf16_f32 %0, %1, %2" : "=v"(w[r2]) : "v"(e0), "v"(e1));
      }
      asm volatile("v_permlane32_swap_b32 %0, %1" : "+v"(w[0]), "+v"(w[2]));
      asm volatile("v_permlane32_swap_b32 %0, %1" : "+v"(w[1]), "+v"(w[3]));
      asm volatile("v_permlane32_swap_b32 %0, %1" : "+v"(w[4]), "+v"(w[6]));
      asm volatile("v_permlane32_swap_b32 %0, %1" : "+v"(w[5]), "+v"(w[7]));
      union U8 { unsigned u[4]; bf16x8 v; };
      U8 pa0, pa1;
      pa0.u[0] = w[0]; pa0.u[1] = w[1]; pa0.u[2] = w[2]; pa0.u[3] = w[3];
      pa1.u[0] = w[4]; pa1.u[1] = w[5]; pa1.u[2] = w[6]; pa1.u[3] = w[7];
      // PV: O[q][d] += P[q][k] * V[d][k]
#pragma unroll
      for (int dt = 0; dt < 2; ++dt) {
        int d = dt * 32 + l31;
        bf16x8 v0 = *(const bf16x8*)&Vs[d * 64 + (((kt * 4 + hi) ^ (d & 7)) * 8)];
        bf16x8 v1 = *(const bf16x8*)&Vs[d * 64 + (((kt * 4 + 2 + hi) ^ (d & 7)) * 8)];
        oacc[dt] = __builtin_amdgcn_mfma_f32_32x32x16_bf16(pa0.v, v0, oacc[dt], 0, 0, 0);
        oacc[dt] = __builtin_amdgcn_mfma_f32_32x32x16_bf16(pa1.v, v1, oacc[dt], 0, 0, 0);
      }
    }
    __syncthreads();
  }

  // Rowsum finalize: lane l31 holds partial for q=l31 (both hi halves disjoint).
  float rsq = rs0 + rs1;
  rsq += __shfl_xor(rsq, 32);
  if (hi == 0) rs_lds[wave * 32 + l31] = rsq;
  __syncthreads();

  float inv[16];
#pragma unroll
  for (int r = 0; r < 16; ++r)
    inv[r] = 1.0f / rs_lds[wave * 32 + (r & 3) + 8 * (r >> 2) + 4 * hi];

  __bf16* obase = (__bf16*)(Opart + (size_t)ks * BATCH * NPIX * C_DIM +
                            ((size_t)b * NPIX + n0 + wave * 32) * C_DIM +
                            h * HDIM + l31);
#pragma unroll
  for (int dt = 0; dt < 2; ++dt)
#pragma unroll
    for (int r = 0; r < 16; ++r) {
      int q = (r & 3) + 8 * (r >> 2) + 4 * hi;
      obase[(size_t)q * C_DIM + dt * 32] = (__bf16)(oacc[dt][r] * inv[r]);
    }
  if (hi == 0)
    rs[(((size_t)ks * 8 + b) * 8 + h) * NPIX + n0 + wave * 32 + l31] = rsq;
}

// ---------------- combine 4 split-K partials: AOT = sum(w_ks * O_ks) -------
__global__ __launch_bounds__(256) void k_comb(const unsigned short* __restrict__ Op,
                                              const float* __restrict__ rs,
                                              unsigned short* __restrict__ AOT) {
  const size_t BIG = (size_t)BATCH * NPIX * C_DIM;
  int i = blockIdx.x * 256 + threadIdx.x;   // 524288 threads, 8 bf16 each
  int b = i >> 16;
  int rem = i & 65535;
  int n = rem >> 6;
  int c8 = rem & 63;
  int h = c8 >> 3;
  size_t off = ((size_t)b * NPIX + n) * C_DIM + c8 * 8;
  float r[4], tot = 0.f;
#pragma unroll
  for (int ks = 0; ks < 4; ++ks) {
    r[ks] = rs[(((size_t)ks * 8 + b) * 8 + h) * NPIX + n];
    tot += r[ks];
  }
  float itot = 1.0f / tot;
  uint4 av[4];
#pragma unroll
  for (int ks = 0; ks < 4; ++ks) av[ks] = *(const uint4*)(Op + ks * BIG + off);
  uint4 o;
  unsigned* ou = (unsigned*)&o;
#pragma unroll
  for (int j = 0; j < 4; ++j) {
    float lo = 0.f, hif = 0.f;
#pragma unroll
    for (int ks = 0; ks < 4; ++ks) {
      unsigned u = ((const unsigned*)&av[ks])[j];
      union { unsigned u; float f; } t;
      float wk = r[ks] * itot;
      t.u = (u & 0xFFFFu) << 16; lo += wk * t.f;
      t.u = u & 0xFFFF0000u;     hif += wk * t.f;
    }
    unsigned pk;
    asm("v_cvt_pk_bf16_f32 %0, %1, %2" : "=v"(pk) : "v"(lo), "v"(hif));
    ou[j] = pk;
  }
  *(uint4*)(AOT + off) = o;
}

// ---------------- proj GEMM + bias + residual (f32 out) ----------------
__global__ __launch_bounds__(256) void k_proj(const unsigned short* __restrict__ Wp,
                                              const float* __restrict__ bp,
                                              const unsigned short* __restrict__ AOT,
                                              const float* __restrict__ x,
                                              float* __restrict__ out) {
  __shared__ unsigned short Atile[128 * 32];
  __shared__ unsigned short Btile[128 * 32];
  const int b = blockIdx.z;
  const int m0 = blockIdx.y * 128, n0 = blockIdx.x * 128;
  const int t = threadIdx.x, wave = t >> 6, lane = t & 63;
  const int wr = wave >> 1, wc = wave & 1;
  f32x4 acc[4][4] = {};
  const int st_row = lane >> 2;
  const int st_col = (((lane & 3) ^ ((lane >> 3) & 3))) * 8;

  for (int k0 = 0; k0 < C_DIM; k0 += 32) {
    __syncthreads();
#pragma unroll
    for (int it = 0; it < 2; ++it) {
      int q = wave + 4 * it;
      int row = q * 16 + st_row;
      gl_lds16(&Wp[(size_t)(m0 + row) * C_DIM + k0 + st_col], &Atile[q * 512]);
      gl_lds16(&AOT[((size_t)b * NPIX + n0 + row) * C_DIM + k0 + st_col], &Btile[q * 512]);
    }
    __syncthreads();
    bf16x8 af[4], bfr[4];
#pragma unroll
    for (int i = 0; i < 4; ++i) {
      int row = wr * 64 + i * 16 + (lane & 15);
      af[i] = *(const bf16x8*)&Atile[row * 32 + (((lane >> 4) ^ ((row >> 1) & 3)) * 8)];
    }
#pragma unroll
    for (int j = 0; j < 4; ++j) {
      int row = wc * 64 + j * 16 + (lane & 15);
      bfr[j] = *(const bf16x8*)&Btile[row * 32 + (((lane >> 4) ^ ((row >> 1) & 3)) * 8)];
    }
#pragma unroll
    for (int i = 0; i < 4; ++i)
#pragma unroll
      for (int j = 0; j < 4; ++j)
        acc[i][j] = __builtin_amdgcn_mfma_f32_16x16x32_bf16(af[i], bfr[j], acc[i][j], 0, 0, 0);
  }

#pragma unroll
  for (int i = 0; i < 4; ++i) {
    int o = m0 + wr * 64 + i * 16 + (lane >> 4) * 4;
    float b0 = bp[o + 0], b1 = bp[o + 1], b2 = bp[o + 2], b3 = bp[o + 3];
#pragma unroll
    for (int j = 0; j < 4; ++j) {
      int n = n0 + wc * 64 + j * 16 + (lane & 15);
      size_t base = ((size_t)b * C_DIM + o) * NPIX + n;
      out[base + 0 * NPIX] = acc[i][j][0] + b0 + x[base + 0 * NPIX];
      out[base + 1 * NPIX] = acc[i][j][1] + b1 + x[base + 1 * NPIX];
      out[base + 2 * NPIX] = acc[i][j][2] + b2 + x[base + 2 * NPIX];
      out[base + 3 * NPIX] = acc[i][j][3] + b3 + x[base + 3 * NPIX];
    }
  }
}

extern "C" void kernel_launch(void* const* d_in, const int* in_sizes, int n_in,
                              void* d_out, int out_size, void* d_ws, size_t ws_size,
                              hipStream_t stream) {
  (void)in_sizes; (void)n_in; (void)out_size; (void)ws_size;
  const float* x     = (const float*)d_in[0];
  const float* gamma = (const float*)d_in[1];
  const float* beta  = (const float*)d_in[2];
  const float* rmean = (const float*)d_in[3];
  const float* rvar  = (const float*)d_in[4];
  const float* wq    = (const float*)d_in[5];
  const float* bq    = (const float*)d_in[6];
  const float* wk    = (const float*)d_in[7];
  const float* bk    = (const float*)d_in[8];
  const float* wv    = (const float*)d_in[9];
  const float* bv    = (const float*)d_in[10];
  const float* wp    = (const float*)d_in[11];
  const float* bp    = (const float*)d_in[12];

  unsigned short* ws  = (unsigned short*)d_ws;
  const size_t WSZ    = (size_t)C_DIM * C_DIM;        // 262144
  const size_t BIG    = (size_t)BATCH * NPIX * C_DIM; // 4194304
  unsigned short* wbf  = ws;                  // 4*WSZ
  unsigned short* hbT  = wbf + 4 * WSZ;
  unsigned short* QT   = hbT + BIG;
  unsigned short* KT   = QT + BIG;
  unsigned short* Vb   = KT + BIG;
  unsigned short* AOT  = Vb + BIG;
  unsigned short* Opart = AOT + BIG;          // 4*BIG
  float*          rs   = (float*)(Opart + 4 * BIG); // 4*8*8*1024 f32 = 1MB

  k_prep<<<dim3(512), dim3(256), 0, stream>>>(wq, wk, wv, wp, wbf);
  k_bnT<<<dim3(16, 8, 8), dim3(256), 0, stream>>>(x, gamma, beta, rmean, rvar, hbT);
  k_qkv<<<dim3(8, 4, 24), dim3(256), 0, stream>>>(wbf, bq, bk, bv, hbT, QT, KT, Vb);
  k_attn<<<dim3(2048), dim3(256), 0, stream>>>(QT, KT, Vb, Opart, rs);
  k_comb<<<dim3(2048), dim3(256), 0, stream>>>(Opart, rs, AOT);
  k_proj<<<dim3(8, 4, 8), dim3(256), 0, stream>>>(wbf + 3 * WSZ, bp, AOT, x, (float*)d_out);
}

// Round 10
// 203.713 us; speedup vs baseline: 1.1286x; 1.1286x over previous
//
#include <hip/hip_runtime.h>
#include <stdint.h>

#define C_DIM 512
#define NHEADS 8
#define HDIM 64
#define BATCH 8
#define NPIX 1024
// Q pre-scale: (1/sqrt(64)) * log2(e) -> exp becomes bare exp2
#define Q_PRESCALE 0.18033688011112042f

typedef __bf16 bf16x8 __attribute__((ext_vector_type(8)));
typedef float f32x4 __attribute__((ext_vector_type(4)));
typedef float f32x16 __attribute__((ext_vector_type(16)));

__device__ __forceinline__ unsigned short f2bf(float f) {
  union { float f; unsigned u; } v; v.f = f;
  unsigned r = v.u + 0x7fffu + ((v.u >> 16) & 1u);
  return (unsigned short)(r >> 16);
}

__device__ __forceinline__ void gl_lds16(const void* g, void* l) {
  __builtin_amdgcn_global_load_lds(
      (__attribute__((address_space(1))) void*)g,
      (__attribute__((address_space(3))) void*)l,
      16, 0, 0);
}

// ---------------- weights f32 -> bf16 ----------------
__global__ __launch_bounds__(256) void k_prep(const float* __restrict__ wq,
                                              const float* __restrict__ wk,
                                              const float* __restrict__ wv,
                                              const float* __restrict__ wp,
                                              unsigned short* __restrict__ wbf) {
  const int n = C_DIM * C_DIM;
  for (int i = blockIdx.x * blockDim.x + threadIdx.x; i < 4 * n;
       i += gridDim.x * blockDim.x) {
    const float* src = (i < n) ? wq : (i < 2 * n) ? wk : (i < 3 * n) ? wv : wp;
    wbf[i] = f2bf(src[i & (n - 1)]);
  }
}

// ---------------- BN (eval) + transpose: x (B,C,N) f32 -> hbT (B,N,C) bf16 ----
__global__ __launch_bounds__(256) void k_bnT(const float* __restrict__ x,
                                             const float* __restrict__ gamma,
                                             const float* __restrict__ beta,
                                             const float* __restrict__ rmean,
                                             const float* __restrict__ rvar,
                                             unsigned short* __restrict__ hbT) {
  __shared__ unsigned short tile[64][72];
  const int b = blockIdx.z, c0 = blockIdx.y * 64, n0 = blockIdx.x * 64;
  const int t = threadIdx.x;
#pragma unroll
  for (int it = 0; it < 4; ++it) {
    int c = it * 16 + (t >> 4);
    int n = (t & 15) * 4;
    const float4 v = *(const float4*)&x[((size_t)b * C_DIM + c0 + c) * NPIX + n0 + n];
    int cc = c0 + c;
    float inv = gamma[cc] * rsqrtf(rvar[cc] + 1e-5f);
    float add = beta[cc] - rmean[cc] * inv;
    tile[c][n + 0] = f2bf(v.x * inv + add);
    tile[c][n + 1] = f2bf(v.y * inv + add);
    tile[c][n + 2] = f2bf(v.z * inv + add);
    tile[c][n + 3] = f2bf(v.w * inv + add);
  }
  __syncthreads();
#pragma unroll
  for (int it = 0; it < 2; ++it) {
    int n = it * 32 + (t >> 3);
    int cj = (t & 7) * 8;
    unsigned short tmp[8];
#pragma unroll
    for (int u = 0; u < 8; ++u) tmp[u] = tile[cj + u][n];
    uint4 pk;
    pk.x = (unsigned)tmp[0] | ((unsigned)tmp[1] << 16);
    pk.y = (unsigned)tmp[2] | ((unsigned)tmp[3] << 16);
    pk.z = (unsigned)tmp[4] | ((unsigned)tmp[5] << 16);
    pk.w = (unsigned)tmp[6] | ((unsigned)tmp[7] << 16);
    *(uint4*)&hbT[((size_t)b * NPIX + n0 + n) * C_DIM + c0 + cj] = pk;
  }
}

// ---------------- QKV GEMM: OUT[o][n] = W h + b  (BK=64, 8 K-steps) --------
// Q,K stored transposed (B,N,C); V stored (B,C,N). Q pre-scaled by Q_PRESCALE.
__global__ __launch_bounds__(256) void k_qkv(const unsigned short* __restrict__ wbf,
                                             const float* __restrict__ bq,
                                             const float* __restrict__ bk,
                                             const float* __restrict__ bv,
                                             const unsigned short* __restrict__ hbT,
                                             unsigned short* __restrict__ QT,
                                             unsigned short* __restrict__ KT,
                                             unsigned short* __restrict__ Vb) {
  __shared__ unsigned short Atile[128 * 64];
  __shared__ unsigned short Btile[128 * 64];
  const int which = blockIdx.z >> 3;
  const int b = blockIdx.z & 7;
  const int m0 = blockIdx.y * 128, n0 = blockIdx.x * 128;
  const unsigned short* W = wbf + (size_t)which * C_DIM * C_DIM;
  const int t = threadIdx.x, wave = t >> 6, lane = t & 63;
  const int wr = wave >> 1, wc = wave & 1;
  f32x4 acc[4][4] = {};

  for (int k0 = 0; k0 < C_DIM; k0 += 64) {
    __syncthreads();
#pragma unroll
    for (int s = 0; s < 4; ++s) {
      int row = s * 32 + wave * 8 + (lane >> 3);
      int srcc = ((lane & 7) ^ (row & 7)) * 8;
      gl_lds16(&W[(size_t)(m0 + row) * C_DIM + k0 + srcc],
               &Atile[(s * 32 + wave * 8) * 64]);
      gl_lds16(&hbT[((size_t)b * NPIX + n0 + row) * C_DIM + k0 + srcc],
               &Btile[(s * 32 + wave * 8) * 64]);
    }
    __syncthreads();
#pragma unroll
    for (int ks2 = 0; ks2 < 2; ++ks2) {
      bf16x8 af[4], bfr[4];
#pragma unroll
      for (int i = 0; i < 4; ++i) {
        int row = wr * 64 + i * 16 + (lane & 15);
        int phys = (ks2 * 4 + (lane >> 4)) ^ (row & 7);
        af[i] = *(const bf16x8*)&Atile[row * 64 + phys * 8];
      }
#pragma unroll
      for (int j = 0; j < 4; ++j) {
        int row = wc * 64 + j * 16 + (lane & 15);
        int phys = (ks2 * 4 + (lane >> 4)) ^ (row & 7);
        bfr[j] = *(const bf16x8*)&Btile[row * 64 + phys * 8];
      }
#pragma unroll
      for (int i = 0; i < 4; ++i)
#pragma unroll
        for (int j = 0; j < 4; ++j)
          acc[i][j] = __builtin_amdgcn_mfma_f32_16x16x32_bf16(af[i], bfr[j], acc[i][j], 0, 0, 0);
    }
  }

  const float* bias = (which == 0) ? bq : (which == 1) ? bk : bv;
  if (which < 2) {
    unsigned short* T = (which == 0) ? QT : KT;
    const float qs = (which == 0) ? Q_PRESCALE : 1.0f;
#pragma unroll
    for (int i = 0; i < 4; ++i) {
      int o = m0 + wr * 64 + i * 16 + (lane >> 4) * 4;
      float b0 = bias[o + 0], b1 = bias[o + 1], b2 = bias[o + 2], b3 = bias[o + 3];
#pragma unroll
      for (int j = 0; j < 4; ++j) {
        int n = n0 + wc * 64 + j * 16 + (lane & 15);
        ushort4 pk;
        pk.x = f2bf((acc[i][j][0] + b0) * qs);
        pk.y = f2bf((acc[i][j][1] + b1) * qs);
        pk.z = f2bf((acc[i][j][2] + b2) * qs);
        pk.w = f2bf((acc[i][j][3] + b3) * qs);
        *(ushort4*)&T[((size_t)b * NPIX + n) * C_DIM + o] = pk;
      }
    }
  } else {
#pragma unroll
    for (int i = 0; i < 4; ++i) {
      int o = m0 + wr * 64 + i * 16 + (lane >> 4) * 4;
#pragma unroll
      for (int j = 0; j < 4; ++j) {
        int n = n0 + wc * 64 + j * 16 + (lane & 15);
#pragma unroll
        for (int r = 0; r < 4; ++r)
          Vb[((size_t)b * C_DIM + o + r) * NPIX + n] = f2bf(acc[i][j][r] + bias[o + r]);
      }
    }
  }
}

// ---------------- attention v7: 8-wave 256-q blocks, split-K x2, dbuf ------
// Grid 512: b=bid&7 (XCD-pinned), h=(bid>>3)&7, qt=(bid>>6)&3, ks=bid>>8.
// Each block: 256 q x 512 kpix. 8 waves (512 thr) -> 4096 waves total with NO
// extra K/V traffic vs r6 (staging amortized over 2x q-rows). 32KB LDS dbuf.
// r8 lesson: more waves must not multiply memory traffic.
__global__ __launch_bounds__(512, 6) void k_attn(const unsigned short* __restrict__ QT,
                                                 const unsigned short* __restrict__ KT,
                                                 const unsigned short* __restrict__ Vb,
                                                 unsigned short* __restrict__ Opart,
                                                 float* __restrict__ rs) {
  __shared__ unsigned short Ks[2][64 * 64];  // [kpix][c], chunk ^= (row&7)
  __shared__ unsigned short Vs[2][64 * 64];  // [d][kpix], chunk ^= (d&7)
  __shared__ float rs_lds[256];

  const int bid = blockIdx.x;
  const int b = bid & 7, h = (bid >> 3) & 7, qt = (bid >> 6) & 3, ks = bid >> 8;
  const int n0 = qt * 256;
  const int kbase0 = ks * 512;
  const int lane = threadIdx.x & 63, wave = threadIdx.x >> 6;
  const int l31 = lane & 31, hi = lane >> 5;

  // Q fragments (B-operand: col q = l31, k = c = kk*16 + hi*8 + j)
  bf16x8 qf[4];
  {
    const unsigned short* qbase =
        QT + ((size_t)b * NPIX + n0 + wave * 32 + l31) * C_DIM + h * HDIM + hi * 8;
#pragma unroll
    for (int kk = 0; kk < 4; ++kk) qf[kk] = *(const bf16x8*)(qbase + kk * 16);
  }

  auto stage = [&](int buf, int tile) {
    const int m0 = kbase0 + tile * 64;
    int rb = wave * 8;                     // 8 waves cover rows 0..63
    int row = rb + (lane >> 3);
    int srcc = ((lane & 7) ^ (row & 7)) * 8;
    gl_lds16(&KT[((size_t)b * NPIX + m0 + row) * C_DIM + h * HDIM + srcc],
             &Ks[buf][rb * 64]);
    gl_lds16(&Vb[((size_t)b * C_DIM + h * HDIM + row) * NPIX + m0 + srcc],
             &Vs[buf][rb * 64]);
  };

  f32x16 oacc[2] = {};
  float rs0 = 0.f, rs1 = 0.f;

  stage(0, 0);
  __syncthreads();

  for (int tile = 0; tile < 8; ++tile) {
    const int cur = tile & 1;
    if (tile < 7) stage(cur ^ 1, tile + 1);

#pragma unroll
    for (int kt = 0; kt < 2; ++kt) {
      // S^T 32x32: A = K [32 kpix x 16 c], B = Q. Lane holds col q=l31.
      f32x16 s = {};
#pragma unroll
      for (int kk = 0; kk < 4; ++kk) {
        int row = kt * 32 + l31;
        int phys = (kk * 2 + hi) ^ (row & 7);
        bf16x8 kf = *(const bf16x8*)&Ks[cur][row * 64 + phys * 8];
        s = __builtin_amdgcn_mfma_f32_32x32x16_bf16(kf, qf[kk], s, 0, 0, 0);
      }
      // P = 2^s (clip-free); rowsum per-lane (q=l31 aligned); pack bf16.
      unsigned w[8];
#pragma unroll
      for (int r2 = 0; r2 < 8; ++r2) {
        float e0 = exp2f(s[2 * r2]);
        float e1 = exp2f(s[2 * r2 + 1]);
        rs0 += e0;
        rs1 += e1;
        asm("v_cvt_pk_bf16_f32 %0, %1, %2" : "=v"(w[r2]) : "v"(e0), "v"(e1));
      }
      asm volatile("v_permlane32_swap_b32 %0, %1" : "+v"(w[0]), "+v"(w[2]));
      asm volatile("v_permlane32_swap_b32 %0, %1" : "+v"(w[1]), "+v"(w[3]));
      asm volatile("v_permlane32_swap_b32 %0, %1" : "+v"(w[4]), "+v"(w[6]));
      asm volatile("v_permlane32_swap_b32 %0, %1" : "+v"(w[5]), "+v"(w[7]));
      union U8 { unsigned u[4]; bf16x8 v; };
      U8 pa0, pa1;
      pa0.u[0] = w[0]; pa0.u[1] = w[1]; pa0.u[2] = w[2]; pa0.u[3] = w[3];
      pa1.u[0] = w[4]; pa1.u[1] = w[5]; pa1.u[2] = w[6]; pa1.u[3] = w[7];
      // PV: O[q][d] += P[q][k] * V[d][k]
#pragma unroll
      for (int dt = 0; dt < 2; ++dt) {
        int d = dt * 32 + l31;
        bf16x8 v0 = *(const bf16x8*)&Vs[cur][d * 64 + (((kt * 4 + hi) ^ (d & 7)) * 8)];
        bf16x8 v1 = *(const bf16x8*)&Vs[cur][d * 64 + (((kt * 4 + 2 + hi) ^ (d & 7)) * 8)];
        oacc[dt] = __builtin_amdgcn_mfma_f32_32x32x16_bf16(pa0.v, v0, oacc[dt], 0, 0, 0);
        oacc[dt] = __builtin_amdgcn_mfma_f32_32x32x16_bf16(pa1.v, v1, oacc[dt], 0, 0, 0);
      }
    }
    __syncthreads();
  }

  // Rowsum finalize: lane l31 holds partial for q=l31 (hi halves disjoint).
  float rsq = rs0 + rs1;
  rsq += __shfl_xor(rsq, 32);
  if (hi == 0) rs_lds[wave * 32 + l31] = rsq;
  __syncthreads();

  float inv[16];
#pragma unroll
  for (int r = 0; r < 16; ++r)
    inv[r] = 1.0f / rs_lds[wave * 32 + (r & 3) + 8 * (r >> 2) + 4 * hi];

  __bf16* obase = (__bf16*)(Opart + (size_t)ks * BATCH * NPIX * C_DIM +
                            ((size_t)b * NPIX + n0 + wave * 32) * C_DIM +
                            h * HDIM + l31);
#pragma unroll
  for (int dt = 0; dt < 2; ++dt)
#pragma unroll
    for (int r = 0; r < 16; ++r) {
      int q = (r & 3) + 8 * (r >> 2) + 4 * hi;
      obase[(size_t)q * C_DIM + dt * 32] = (__bf16)(oacc[dt][r] * inv[r]);
    }
  if (hi == 0)
    rs[(((size_t)ks * 8 + b) * 8 + h) * NPIX + n0 + wave * 32 + l31] = rsq;
}

// ---------------- combine split-K partials: AOT = (rsA*OA + rsB*OB)/(rsA+rsB)
__global__ __launch_bounds__(256) void k_comb(const unsigned short* OA,
                                              const unsigned short* OB,
                                              const float* __restrict__ rs,
                                              unsigned short* AOT) {
  int i = blockIdx.x * 256 + threadIdx.x;   // 524288 threads, 8 bf16 each
  int b = i >> 16;
  int rem = i & 65535;
  int n = rem >> 6;
  int c8 = rem & 63;
  int h = c8 >> 3;
  size_t off = ((size_t)b * NPIX + n) * C_DIM + c8 * 8;
  float rsA = rs[(((size_t)0 * 8 + b) * 8 + h) * NPIX + n];
  float rsB = rs[(((size_t)1 * 8 + b) * 8 + h) * NPIX + n];
  float sA = rsA / (rsA + rsB);
  float sB = 1.0f - sA;
  uint4 a = *(const uint4*)(OA + off);
  uint4 bb = *(const uint4*)(OB + off);
  const unsigned* au = (const unsigned*)&a;
  const unsigned* bu = (const unsigned*)&bb;
  uint4 o;
  unsigned* ou = (unsigned*)&o;
#pragma unroll
  for (int j = 0; j < 4; ++j) {
    float a0, a1, b0, b1;
    union { unsigned u; float f; } t;
    t.u = (au[j] & 0xFFFFu) << 16; a0 = t.f;
    t.u = au[j] & 0xFFFF0000u;     a1 = t.f;
    t.u = (bu[j] & 0xFFFFu) << 16; b0 = t.f;
    t.u = bu[j] & 0xFFFF0000u;     b1 = t.f;
    float o0 = sA * a0 + sB * b0;
    float o1 = sA * a1 + sB * b1;
    unsigned pk;
    asm("v_cvt_pk_bf16_f32 %0, %1, %2" : "=v"(pk) : "v"(o0), "v"(o1));
    ou[j] = pk;
  }
  *(uint4*)(AOT + off) = o;
}

// ---------------- proj GEMM + bias + residual (f32 out) ----------------
__global__ __launch_bounds__(256) void k_proj(const unsigned short* __restrict__ Wp,
                                              const float* __restrict__ bp,
                                              const unsigned short* __restrict__ AOT,
                                              const float* __restrict__ x,
                                              float* __restrict__ out) {
  __shared__ unsigned short Atile[128 * 32];
  __shared__ unsigned short Btile[128 * 32];
  const int b = blockIdx.z;
  const int m0 = blockIdx.y * 128, n0 = blockIdx.x * 128;
  const int t = threadIdx.x, wave = t >> 6, lane = t & 63;
  const int wr = wave >> 1, wc = wave & 1;
  f32x4 acc[4][4] = {};
  const int st_row = lane >> 2;
  const int st_col = (((lane & 3) ^ ((lane >> 3) & 3))) * 8;

  for (int k0 = 0; k0 < C_DIM; k0 += 32) {
    __syncthreads();
#pragma unroll
    for (int it = 0; it < 2; ++it) {
      int q = wave + 4 * it;
      int row = q * 16 + st_row;
      gl_lds16(&Wp[(size_t)(m0 + row) * C_DIM + k0 + st_col], &Atile[q * 512]);
      gl_lds16(&AOT[((size_t)b * NPIX + n0 + row) * C_DIM + k0 + st_col], &Btile[q * 512]);
    }
    __syncthreads();
    bf16x8 af[4], bfr[4];
#pragma unroll
    for (int i = 0; i < 4; ++i) {
      int row = wr * 64 + i * 16 + (lane & 15);
      af[i] = *(const bf16x8*)&Atile[row * 32 + (((lane >> 4) ^ ((row >> 1) & 3)) * 8)];
    }
#pragma unroll
    for (int j = 0; j < 4; ++j) {
      int row = wc * 64 + j * 16 + (lane & 15);
      bfr[j] = *(const bf16x8*)&Btile[row * 32 + (((lane >> 4) ^ ((row >> 1) & 3)) * 8)];
    }
#pragma unroll
    for (int i = 0; i < 4; ++i)
#pragma unroll
      for (int j = 0; j < 4; ++j)
        acc[i][j] = __builtin_amdgcn_mfma_f32_16x16x32_bf16(af[i], bfr[j], acc[i][j], 0, 0, 0);
  }

#pragma unroll
  for (int i = 0; i < 4; ++i) {
    int o = m0 + wr * 64 + i * 16 + (lane >> 4) * 4;
    float b0 = bp[o + 0], b1 = bp[o + 1], b2 = bp[o + 2], b3 = bp[o + 3];
#pragma unroll
    for (int j = 0; j < 4; ++j) {
      int n = n0 + wc * 64 + j * 16 + (lane & 15);
      size_t base = ((size_t)b * C_DIM + o) * NPIX + n;
      out[base + 0 * NPIX] = acc[i][j][0] + b0 + x[base + 0 * NPIX];
      out[base + 1 * NPIX] = acc[i][j][1] + b1 + x[base + 1 * NPIX];
      out[base + 2 * NPIX] = acc[i][j][2] + b2 + x[base + 2 * NPIX];
      out[base + 3 * NPIX] = acc[i][j][3] + b3 + x[base + 3 * NPIX];
    }
  }
}

extern "C" void kernel_launch(void* const* d_in, const int* in_sizes, int n_in,
                              void* d_out, int out_size, void* d_ws, size_t ws_size,
                              hipStream_t stream) {
  (void)in_sizes; (void)n_in; (void)out_size; (void)ws_size;
  const float* x     = (const float*)d_in[0];
  const float* gamma = (const float*)d_in[1];
  const float* beta  = (const float*)d_in[2];
  const float* rmean = (const float*)d_in[3];
  const float* rvar  = (const float*)d_in[4];
  const float* wq    = (const float*)d_in[5];
  const float* bq    = (const float*)d_in[6];
  const float* wk    = (const float*)d_in[7];
  const float* bk    = (const float*)d_in[8];
  const float* wv    = (const float*)d_in[9];
  const float* bv    = (const float*)d_in[10];
  const float* wp    = (const float*)d_in[11];
  const float* bp    = (const float*)d_in[12];

  unsigned short* ws  = (unsigned short*)d_ws;
  const size_t WSZ    = (size_t)C_DIM * C_DIM;        // 262144
  const size_t BIG    = (size_t)BATCH * NPIX * C_DIM; // 4194304
  unsigned short* wbf   = ws;                  // 4*WSZ
  unsigned short* hbT   = wbf + 4 * WSZ;
  unsigned short* QT    = hbT + BIG;
  unsigned short* KT    = QT + BIG;
  unsigned short* Vb    = KT + BIG;
  unsigned short* AOT   = Vb + BIG;
  unsigned short* Opart = AOT + BIG;           // 2*BIG
  float*          rs    = (float*)(Opart + 2 * BIG); // 2*8*8*1024 f32 = 512KB

  k_prep<<<dim3(512), dim3(256), 0, stream>>>(wq, wk, wv, wp, wbf);
  k_bnT<<<dim3(16, 8, 8), dim3(256), 0, stream>>>(x, gamma, beta, rmean, rvar, hbT);
  k_qkv<<<dim3(8, 4, 24), dim3(256), 0, stream>>>(wbf, bq, bk, bv, hbT, QT, KT, Vb);
  k_attn<<<dim3(512), dim3(512), 0, stream>>>(QT, KT, Vb, Opart, rs);
  k_comb<<<dim3(2048), dim3(256), 0, stream>>>(Opart, Opart + BIG, rs, AOT);
  k_proj<<<dim3(8, 4, 8), dim3(256), 0, stream>>>(wbf + 3 * WSZ, bp, AOT, x, (float*)d_out);
}

// Round 11
// 179.437 us; speedup vs baseline: 1.2812x; 1.1353x over previous
//
#include <hip/hip_runtime.h>
#include <stdint.h>

#define C_DIM 512
#define NHEADS 8
#define HDIM 64
#define BATCH 8
#define NPIX 1024
// Q pre-scale: (1/sqrt(64)) * log2(e) -> exp becomes bare exp2
#define Q_PRESCALE 0.18033688011112042f

typedef __bf16 bf16x8 __attribute__((ext_vector_type(8)));
typedef float f32x4 __attribute__((ext_vector_type(4)));
typedef float f32x16 __attribute__((ext_vector_type(16)));

__device__ __forceinline__ unsigned short f2bf(float f) {
  union { float f; unsigned u; } v; v.f = f;
  unsigned r = v.u + 0x7fffu + ((v.u >> 16) & 1u);
  return (unsigned short)(r >> 16);
}

__device__ __forceinline__ void gl_lds16(const void* g, void* l) {
  __builtin_amdgcn_global_load_lds(
      (__attribute__((address_space(1))) void*)g,
      (__attribute__((address_space(3))) void*)l,
      16, 0, 0);
}

// ---------------- weights f32 -> bf16 ----------------
__global__ __launch_bounds__(256) void k_prep(const float* __restrict__ wq,
                                              const float* __restrict__ wk,
                                              const float* __restrict__ wv,
                                              const float* __restrict__ wp,
                                              unsigned short* __restrict__ wbf) {
  const int n = C_DIM * C_DIM;
  for (int i = blockIdx.x * blockDim.x + threadIdx.x; i < 4 * n;
       i += gridDim.x * blockDim.x) {
    const float* src = (i < n) ? wq : (i < 2 * n) ? wk : (i < 3 * n) ? wv : wp;
    wbf[i] = f2bf(src[i & (n - 1)]);
  }
}

// ---------------- BN (eval) + transpose: x (B,C,N) f32 -> hbT (B,N,C) bf16 ----
__global__ __launch_bounds__(256) void k_bnT(const float* __restrict__ x,
                                             const float* __restrict__ gamma,
                                             const float* __restrict__ beta,
                                             const float* __restrict__ rmean,
                                             const float* __restrict__ rvar,
                                             unsigned short* __restrict__ hbT) {
  __shared__ unsigned short tile[64][72];
  const int b = blockIdx.z, c0 = blockIdx.y * 64, n0 = blockIdx.x * 64;
  const int t = threadIdx.x;
#pragma unroll
  for (int it = 0; it < 4; ++it) {
    int c = it * 16 + (t >> 4);
    int n = (t & 15) * 4;
    const float4 v = *(const float4*)&x[((size_t)b * C_DIM + c0 + c) * NPIX + n0 + n];
    int cc = c0 + c;
    float inv = gamma[cc] * rsqrtf(rvar[cc] + 1e-5f);
    float add = beta[cc] - rmean[cc] * inv;
    tile[c][n + 0] = f2bf(v.x * inv + add);
    tile[c][n + 1] = f2bf(v.y * inv + add);
    tile[c][n + 2] = f2bf(v.z * inv + add);
    tile[c][n + 3] = f2bf(v.w * inv + add);
  }
  __syncthreads();
#pragma unroll
  for (int it = 0; it < 2; ++it) {
    int n = it * 32 + (t >> 3);
    int cj = (t & 7) * 8;
    unsigned short tmp[8];
#pragma unroll
    for (int u = 0; u < 8; ++u) tmp[u] = tile[cj + u][n];
    uint4 pk;
    pk.x = (unsigned)tmp[0] | ((unsigned)tmp[1] << 16);
    pk.y = (unsigned)tmp[2] | ((unsigned)tmp[3] << 16);
    pk.z = (unsigned)tmp[4] | ((unsigned)tmp[5] << 16);
    pk.w = (unsigned)tmp[6] | ((unsigned)tmp[7] << 16);
    *(uint4*)&hbT[((size_t)b * NPIX + n0 + n) * C_DIM + c0 + cj] = pk;
  }
}

// ---------------- QKV GEMM: OUT[o][n] = W h + b  (BK=64, 8 K-steps) --------
// Q,K stored transposed (B,N,C); V stored (B,C,N). Q pre-scaled by Q_PRESCALE.
__global__ __launch_bounds__(256) void k_qkv(const unsigned short* __restrict__ wbf,
                                             const float* __restrict__ bq,
                                             const float* __restrict__ bk,
                                             const float* __restrict__ bv,
                                             const unsigned short* __restrict__ hbT,
                                             unsigned short* __restrict__ QT,
                                             unsigned short* __restrict__ KT,
                                             unsigned short* __restrict__ Vb) {
  __shared__ unsigned short Atile[128 * 64];
  __shared__ unsigned short Btile[128 * 64];
  const int which = blockIdx.z >> 3;
  const int b = blockIdx.z & 7;
  const int m0 = blockIdx.y * 128, n0 = blockIdx.x * 128;
  const unsigned short* W = wbf + (size_t)which * C_DIM * C_DIM;
  const int t = threadIdx.x, wave = t >> 6, lane = t & 63;
  const int wr = wave >> 1, wc = wave & 1;
  f32x4 acc[4][4] = {};

  for (int k0 = 0; k0 < C_DIM; k0 += 64) {
    __syncthreads();
#pragma unroll
    for (int s = 0; s < 4; ++s) {
      int row = s * 32 + wave * 8 + (lane >> 3);
      int srcc = ((lane & 7) ^ (row & 7)) * 8;
      gl_lds16(&W[(size_t)(m0 + row) * C_DIM + k0 + srcc],
               &Atile[(s * 32 + wave * 8) * 64]);
      gl_lds16(&hbT[((size_t)b * NPIX + n0 + row) * C_DIM + k0 + srcc],
               &Btile[(s * 32 + wave * 8) * 64]);
    }
    __syncthreads();
#pragma unroll
    for (int ks2 = 0; ks2 < 2; ++ks2) {
      bf16x8 af[4], bfr[4];
#pragma unroll
      for (int i = 0; i < 4; ++i) {
        int row = wr * 64 + i * 16 + (lane & 15);
        int phys = (ks2 * 4 + (lane >> 4)) ^ (row & 7);
        af[i] = *(const bf16x8*)&Atile[row * 64 + phys * 8];
      }
#pragma unroll
      for (int j = 0; j < 4; ++j) {
        int row = wc * 64 + j * 16 + (lane & 15);
        int phys = (ks2 * 4 + (lane >> 4)) ^ (row & 7);
        bfr[j] = *(const bf16x8*)&Btile[row * 64 + phys * 8];
      }
#pragma unroll
      for (int i = 0; i < 4; ++i)
#pragma unroll
        for (int j = 0; j < 4; ++j)
          acc[i][j] = __builtin_amdgcn_mfma_f32_16x16x32_bf16(af[i], bfr[j], acc[i][j], 0, 0, 0);
    }
  }

  const float* bias = (which == 0) ? bq : (which == 1) ? bk : bv;
  if (which < 2) {
    unsigned short* T = (which == 0) ? QT : KT;
    const float qs = (which == 0) ? Q_PRESCALE : 1.0f;
#pragma unroll
    for (int i = 0; i < 4; ++i) {
      int o = m0 + wr * 64 + i * 16 + (lane >> 4) * 4;
      float b0 = bias[o + 0], b1 = bias[o + 1], b2 = bias[o + 2], b3 = bias[o + 3];
#pragma unroll
      for (int j = 0; j < 4; ++j) {
        int n = n0 + wc * 64 + j * 16 + (lane & 15);
        ushort4 pk;
        pk.x = f2bf((acc[i][j][0] + b0) * qs);
        pk.y = f2bf((acc[i][j][1] + b1) * qs);
        pk.z = f2bf((acc[i][j][2] + b2) * qs);
        pk.w = f2bf((acc[i][j][3] + b3) * qs);
        *(ushort4*)&T[((size_t)b * NPIX + n) * C_DIM + o] = pk;
      }
    }
  } else {
#pragma unroll
    for (int i = 0; i < 4; ++i) {
      int o = m0 + wr * 64 + i * 16 + (lane >> 4) * 4;
#pragma unroll
      for (int j = 0; j < 4; ++j) {
        int n = n0 + wc * 64 + j * 16 + (lane & 15);
#pragma unroll
        for (int r = 0; r < 4; ++r)
          Vb[((size_t)b * C_DIM + o + r) * NPIX + n] = f2bf(acc[i][j][r] + bias[o + r]);
      }
    }
  }
}

// ---------------- attention v8: r6-v4 structure + VALU rowsum + merged store
// Grid 1024: b=bid&7 (XCD-pinned), h=(bid>>3)&7, qt=(bid>>6)&7, ks=bid>>9.
// 128 q x 512 kpix per block, 4 waves, dbuf-2 (32KB), one barrier per tile.
// Store r-outer/dt-inner so both 64B halves of each 128B line are adjacent.
__global__ __launch_bounds__(256) void k_attn(const unsigned short* __restrict__ QT,
                                              const unsigned short* __restrict__ KT,
                                              const unsigned short* __restrict__ Vb,
                                              unsigned short* __restrict__ Opart,
                                              float* __restrict__ rs) {
  __shared__ unsigned short Ks[2][64 * 64];  // [kpix][c], chunk ^= (row&7)
  __shared__ unsigned short Vs[2][64 * 64];  // [d][kpix], chunk ^= (d&7)
  __shared__ float rs_lds[128];

  const int bid = blockIdx.x;
  const int b = bid & 7, h = (bid >> 3) & 7, qt = (bid >> 6) & 7, ks = bid >> 9;
  const int n0 = qt * 128;
  const int kbase0 = ks * 512;
  const int lane = threadIdx.x & 63, wave = threadIdx.x >> 6;
  const int l31 = lane & 31, hi = lane >> 5;

  // Q fragments (B-operand: col q = l31, k = c = kk*16 + hi*8 + j)
  bf16x8 qf[4];
  {
    const unsigned short* qbase =
        QT + ((size_t)b * NPIX + n0 + wave * 32 + l31) * C_DIM + h * HDIM + hi * 8;
#pragma unroll
    for (int kk = 0; kk < 4; ++kk) qf[kk] = *(const bf16x8*)(qbase + kk * 16);
  }

  auto stage = [&](int buf, int tile) {
    const int m0 = kbase0 + tile * 64;
#pragma unroll
    for (int it = 0; it < 2; ++it) {
      int rb = it * 32 + wave * 8;
      int row = rb + (lane >> 3);
      int srcc = ((lane & 7) ^ (row & 7)) * 8;
      gl_lds16(&KT[((size_t)b * NPIX + m0 + row) * C_DIM + h * HDIM + srcc],
               &Ks[buf][rb * 64]);
      gl_lds16(&Vb[((size_t)b * C_DIM + h * HDIM + row) * NPIX + m0 + srcc],
               &Vs[buf][rb * 64]);
    }
  };

  f32x16 oacc[2] = {};
  float rs0 = 0.f, rs1 = 0.f;

  stage(0, 0);
  __syncthreads();

  for (int tile = 0; tile < 8; ++tile) {
    const int cur = tile & 1;
    if (tile < 7) stage(cur ^ 1, tile + 1);

#pragma unroll
    for (int kt = 0; kt < 2; ++kt) {
      // S^T 32x32: A = K [32 kpix x 16 c], B = Q. Lane holds col q=l31.
      f32x16 s = {};
#pragma unroll
      for (int kk = 0; kk < 4; ++kk) {
        int row = kt * 32 + l31;
        int phys = (kk * 2 + hi) ^ (row & 7);
        bf16x8 kf = *(const bf16x8*)&Ks[cur][row * 64 + phys * 8];
        s = __builtin_amdgcn_mfma_f32_32x32x16_bf16(kf, qf[kk], s, 0, 0, 0);
      }
      // P = 2^s (clip-free); rowsum per-lane (q=l31 aligned); pack bf16.
      unsigned w[8];
#pragma unroll
      for (int r2 = 0; r2 < 8; ++r2) {
        float e0 = exp2f(s[2 * r2]);
        float e1 = exp2f(s[2 * r2 + 1]);
        rs0 += e0;
        rs1 += e1;
        asm("v_cvt_pk_bf16_f32 %0, %1, %2" : "=v"(w[r2]) : "v"(e0), "v"(e1));
      }
      asm volatile("v_permlane32_swap_b32 %0, %1" : "+v"(w[0]), "+v"(w[2]));
      asm volatile("v_permlane32_swap_b32 %0, %1" : "+v"(w[1]), "+v"(w[3]));
      asm volatile("v_permlane32_swap_b32 %0, %1" : "+v"(w[4]), "+v"(w[6]));
      asm volatile("v_permlane32_swap_b32 %0, %1" : "+v"(w[5]), "+v"(w[7]));
      union U8 { unsigned u[4]; bf16x8 v; };
      U8 pa0, pa1;
      pa0.u[0] = w[0]; pa0.u[1] = w[1]; pa0.u[2] = w[2]; pa0.u[3] = w[3];
      pa1.u[0] = w[4]; pa1.u[1] = w[5]; pa1.u[2] = w[6]; pa1.u[3] = w[7];
      // PV: O[q][d] += P[q][k] * V[d][k]
#pragma unroll
      for (int dt = 0; dt < 2; ++dt) {
        int d = dt * 32 + l31;
        bf16x8 v0 = *(const bf16x8*)&Vs[cur][d * 64 + (((kt * 4 + hi) ^ (d & 7)) * 8)];
        bf16x8 v1 = *(const bf16x8*)&Vs[cur][d * 64 + (((kt * 4 + 2 + hi) ^ (d & 7)) * 8)];
        oacc[dt] = __builtin_amdgcn_mfma_f32_32x32x16_bf16(pa0.v, v0, oacc[dt], 0, 0, 0);
        oacc[dt] = __builtin_amdgcn_mfma_f32_32x32x16_bf16(pa1.v, v1, oacc[dt], 0, 0, 0);
      }
    }
    __syncthreads();
  }

  // Rowsum finalize: lane l31 holds partial for q=l31 (hi halves disjoint).
  float rsq = rs0 + rs1;
  rsq += __shfl_xor(rsq, 32);
  if (hi == 0) rs_lds[wave * 32 + l31] = rsq;
  __syncthreads();

  float inv[16];
#pragma unroll
  for (int r = 0; r < 16; ++r)
    inv[r] = 1.0f / rs_lds[wave * 32 + (r & 3) + 8 * (r >> 2) + 4 * hi];

  __bf16* obase = (__bf16*)(Opart + (size_t)ks * BATCH * NPIX * C_DIM +
                            ((size_t)b * NPIX + n0 + wave * 32) * C_DIM +
                            h * HDIM + l31);
  // r outer, dt inner: both 64B halves of each 128B line issue back-to-back.
#pragma unroll
  for (int r = 0; r < 16; ++r) {
    int q = (r & 3) + 8 * (r >> 2) + 4 * hi;
#pragma unroll
    for (int dt = 0; dt < 2; ++dt)
      obase[(size_t)q * C_DIM + dt * 32] = (__bf16)(oacc[dt][r] * inv[r]);
  }
  if (hi == 0)
    rs[(((size_t)ks * 8 + b) * 8 + h) * NPIX + n0 + wave * 32 + l31] = rsq;
}

// ---------------- proj GEMM + fused split-K combine + bias + residual ------
// B-operand = (rsA*OA + rsB*OB)/(rsA+rsB) combined in registers during the
// staging phase, written to LDS in the exact image gl_lds16 produced before.
__global__ __launch_bounds__(256) void k_proj(const unsigned short* __restrict__ Wp,
                                              const float* __restrict__ bp,
                                              const unsigned short* __restrict__ OpA,
                                              const unsigned short* __restrict__ OpB,
                                              const float* __restrict__ rs,
                                              const float* __restrict__ x,
                                              float* __restrict__ out) {
  __shared__ unsigned short Atile[128 * 32];
  __shared__ unsigned short Btile[128 * 32];
  const int b = blockIdx.z;
  const int m0 = blockIdx.y * 128, n0 = blockIdx.x * 128;
  const int t = threadIdx.x, wave = t >> 6, lane = t & 63;
  const int wr = wave >> 1, wc = wave & 1;
  f32x4 acc[4][4] = {};
  const int st_row = lane >> 2;
  const int st_col = (((lane & 3) ^ ((lane >> 3) & 3))) * 8;

  for (int k0 = 0; k0 < C_DIM; k0 += 32) {
    __syncthreads();
    const int hh = (k0 + st_col) >> 6;
#pragma unroll
    for (int it = 0; it < 2; ++it) {
      int q = wave + 4 * it;
      int row = q * 16 + st_row;
      gl_lds16(&Wp[(size_t)(m0 + row) * C_DIM + k0 + st_col], &Atile[q * 512]);
      // B: combine Opart halves in registers -> ds_write (same LDS image)
      int n = n0 + row;
      float rsA = rs[((size_t)(0 * 8 + b) * 8 + hh) * NPIX + n];
      float rsB = rs[((size_t)(1 * 8 + b) * 8 + hh) * NPIX + n];
      float sA = rsA / (rsA + rsB);
      float sB = 1.0f - sA;
      size_t off = ((size_t)b * NPIX + n) * C_DIM + k0 + st_col;
      uint4 ua = *(const uint4*)(OpA + off);
      uint4 ub = *(const uint4*)(OpB + off);
      const unsigned* au = (const unsigned*)&ua;
      const unsigned* bu = (const unsigned*)&ub;
      uint4 o;
      unsigned* ou = (unsigned*)&o;
#pragma unroll
      for (int j = 0; j < 4; ++j) {
        union { unsigned u; float f; } tt;
        float a0, a1, b0, b1;
        tt.u = (au[j] & 0xFFFFu) << 16; a0 = tt.f;
        tt.u = au[j] & 0xFFFF0000u;     a1 = tt.f;
        tt.u = (bu[j] & 0xFFFFu) << 16; b0 = tt.f;
        tt.u = bu[j] & 0xFFFF0000u;     b1 = tt.f;
        float o0 = sA * a0 + sB * b0;
        float o1 = sA * a1 + sB * b1;
        unsigned pk;
        asm("v_cvt_pk_bf16_f32 %0, %1, %2" : "=v"(pk) : "v"(o0), "v"(o1));
        ou[j] = pk;
      }
      *(uint4*)&Btile[q * 512 + lane * 8] = o;
    }
    __syncthreads();
    bf16x8 af[4], bfr[4];
#pragma unroll
    for (int i = 0; i < 4; ++i) {
      int row = wr * 64 + i * 16 + (lane & 15);
      af[i] = *(const bf16x8*)&Atile[row * 32 + (((lane >> 4) ^ ((row >> 1) & 3)) * 8)];
    }
#pragma unroll
    for (int j = 0; j < 4; ++j) {
      int row = wc * 64 + j * 16 + (lane & 15);
      bfr[j] = *(const bf16x8*)&Btile[row * 32 + (((lane >> 4) ^ ((row >> 1) & 3)) * 8)];
    }
#pragma unroll
    for (int i = 0; i < 4; ++i)
#pragma unroll
      for (int j = 0; j < 4; ++j)
        acc[i][j] = __builtin_amdgcn_mfma_f32_16x16x32_bf16(af[i], bfr[j], acc[i][j], 0, 0, 0);
  }

#pragma unroll
  for (int i = 0; i < 4; ++i) {
    int o = m0 + wr * 64 + i * 16 + (lane >> 4) * 4;
    float b0 = bp[o + 0], b1 = bp[o + 1], b2 = bp[o + 2], b3 = bp[o + 3];
#pragma unroll
    for (int j = 0; j < 4; ++j) {
      int n = n0 + wc * 64 + j * 16 + (lane & 15);
      size_t base = ((size_t)b * C_DIM + o) * NPIX + n;
      out[base + 0 * NPIX] = acc[i][j][0] + b0 + x[base + 0 * NPIX];
      out[base + 1 * NPIX] = acc[i][j][1] + b1 + x[base + 1 * NPIX];
      out[base + 2 * NPIX] = acc[i][j][2] + b2 + x[base + 2 * NPIX];
      out[base + 3 * NPIX] = acc[i][j][3] + b3 + x[base + 3 * NPIX];
    }
  }
}

extern "C" void kernel_launch(void* const* d_in, const int* in_sizes, int n_in,
                              void* d_out, int out_size, void* d_ws, size_t ws_size,
                              hipStream_t stream) {
  (void)in_sizes; (void)n_in; (void)out_size; (void)ws_size;
  const float* x     = (const float*)d_in[0];
  const float* gamma = (const float*)d_in[1];
  const float* beta  = (const float*)d_in[2];
  const float* rmean = (const float*)d_in[3];
  const float* rvar  = (const float*)d_in[4];
  const float* wq    = (const float*)d_in[5];
  const float* bq    = (const float*)d_in[6];
  const float* wk    = (const float*)d_in[7];
  const float* bk    = (const float*)d_in[8];
  const float* wv    = (const float*)d_in[9];
  const float* bv    = (const float*)d_in[10];
  const float* wp    = (const float*)d_in[11];
  const float* bp    = (const float*)d_in[12];

  unsigned short* ws  = (unsigned short*)d_ws;
  const size_t WSZ    = (size_t)C_DIM * C_DIM;        // 262144
  const size_t BIG    = (size_t)BATCH * NPIX * C_DIM; // 4194304
  unsigned short* wbf   = ws;                  // 4*WSZ
  unsigned short* hbT   = wbf + 4 * WSZ;
  unsigned short* QT    = hbT + BIG;
  unsigned short* KT    = QT + BIG;
  unsigned short* Vb    = KT + BIG;
  unsigned short* Opart = Vb + BIG;            // 2*BIG
  float*          rs    = (float*)(Opart + 2 * BIG); // 2*8*8*1024 f32 = 512KB

  k_prep<<<dim3(512), dim3(256), 0, stream>>>(wq, wk, wv, wp, wbf);
  k_bnT<<<dim3(16, 8, 8), dim3(256), 0, stream>>>(x, gamma, beta, rmean, rvar, hbT);
  k_qkv<<<dim3(8, 4, 24), dim3(256), 0, stream>>>(wbf, bq, bk, bv, hbT, QT, KT, Vb);
  k_attn<<<dim3(1024), dim3(256), 0, stream>>>(QT, KT, Vb, Opart, rs);
  k_proj<<<dim3(8, 4, 8), dim3(256), 0, stream>>>(wbf + 3 * WSZ, bp, Opart, Opart + BIG, rs, x, (float*)d_out);
}

// Round 12
// 177.904 us; speedup vs baseline: 1.2923x; 1.0086x over previous
//
#include <hip/hip_runtime.h>
#include <stdint.h>

#define C_DIM 512
#define NHEADS 8
#define HDIM 64
#define BATCH 8
#define NPIX 1024
// Q pre-scale: (1/sqrt(64)) * log2(e) -> exp becomes bare exp2
#define Q_PRESCALE 0.18033688011112042f

typedef __bf16 bf16x8 __attribute__((ext_vector_type(8)));
typedef float f32x4 __attribute__((ext_vector_type(4)));
typedef float f32x16 __attribute__((ext_vector_type(16)));

__device__ __forceinline__ unsigned short f2bf(float f) {
  union { float f; unsigned u; } v; v.f = f;
  unsigned r = v.u + 0x7fffu + ((v.u >> 16) & 1u);
  return (unsigned short)(r >> 16);
}

__device__ __forceinline__ void gl_lds16(const void* g, void* l) {
  __builtin_amdgcn_global_load_lds(
      (__attribute__((address_space(1))) void*)g,
      (__attribute__((address_space(3))) void*)l,
      16, 0, 0);
}

// ---------------- weights f32 -> bf16 ----------------
__global__ __launch_bounds__(256) void k_prep(const float* __restrict__ wq,
                                              const float* __restrict__ wk,
                                              const float* __restrict__ wv,
                                              const float* __restrict__ wp,
                                              unsigned short* __restrict__ wbf) {
  const int n = C_DIM * C_DIM;
  for (int i = blockIdx.x * blockDim.x + threadIdx.x; i < 4 * n;
       i += gridDim.x * blockDim.x) {
    const float* src = (i < n) ? wq : (i < 2 * n) ? wk : (i < 3 * n) ? wv : wp;
    wbf[i] = f2bf(src[i & (n - 1)]);
  }
}

// ---------------- BN (eval) + transpose: x (B,C,N) f32 -> hbT (B,N,C) bf16 ----
__global__ __launch_bounds__(256) void k_bnT(const float* __restrict__ x,
                                             const float* __restrict__ gamma,
                                             const float* __restrict__ beta,
                                             const float* __restrict__ rmean,
                                             const float* __restrict__ rvar,
                                             unsigned short* __restrict__ hbT) {
  __shared__ unsigned short tile[64][72];
  const int b = blockIdx.z, c0 = blockIdx.y * 64, n0 = blockIdx.x * 64;
  const int t = threadIdx.x;
#pragma unroll
  for (int it = 0; it < 4; ++it) {
    int c = it * 16 + (t >> 4);
    int n = (t & 15) * 4;
    const float4 v = *(const float4*)&x[((size_t)b * C_DIM + c0 + c) * NPIX + n0 + n];
    int cc = c0 + c;
    float inv = gamma[cc] * rsqrtf(rvar[cc] + 1e-5f);
    float add = beta[cc] - rmean[cc] * inv;
    tile[c][n + 0] = f2bf(v.x * inv + add);
    tile[c][n + 1] = f2bf(v.y * inv + add);
    tile[c][n + 2] = f2bf(v.z * inv + add);
    tile[c][n + 3] = f2bf(v.w * inv + add);
  }
  __syncthreads();
#pragma unroll
  for (int it = 0; it < 2; ++it) {
    int n = it * 32 + (t >> 3);
    int cj = (t & 7) * 8;
    unsigned short tmp[8];
#pragma unroll
    for (int u = 0; u < 8; ++u) tmp[u] = tile[cj + u][n];
    uint4 pk;
    pk.x = (unsigned)tmp[0] | ((unsigned)tmp[1] << 16);
    pk.y = (unsigned)tmp[2] | ((unsigned)tmp[3] << 16);
    pk.z = (unsigned)tmp[4] | ((unsigned)tmp[5] << 16);
    pk.w = (unsigned)tmp[6] | ((unsigned)tmp[7] << 16);
    *(uint4*)&hbT[((size_t)b * NPIX + n0 + n) * C_DIM + c0 + cj] = pk;
  }
}

// ---------------- fused QKV GEMM: one block computes Q,K,V for same tile ----
// B (hbT) staged ONCE per block and shared by 3 A-tiles (wq/wk/wv rows).
// 48 MFMA per barrier-pair (3x old density). M-tile 64, N-tile 128, BK=64.
// Q,K stored transposed (B,N,C), Q pre-scaled; V stored (B,C,N).
__global__ __launch_bounds__(256) void k_qkv(const unsigned short* __restrict__ wbf,
                                             const float* __restrict__ bq,
                                             const float* __restrict__ bk,
                                             const float* __restrict__ bv,
                                             const unsigned short* __restrict__ hbT,
                                             unsigned short* __restrict__ QT,
                                             unsigned short* __restrict__ KT,
                                             unsigned short* __restrict__ Vb) {
  __shared__ unsigned short At[3][64 * 64];   // [w3][row][k], chunk ^= (row&7)
  __shared__ unsigned short Bt[128 * 64];     // [n-row][k],  chunk ^= (row&7)
  const int b = blockIdx.z;
  const int m0 = blockIdx.y * 64, n0 = blockIdx.x * 128;
  const int t = threadIdx.x, wave = t >> 6, lane = t & 63;
  const int wr = wave >> 1, wc = wave & 1;
  f32x4 acc[3][2][4] = {};

  const int row8 = wave * 8 + (lane >> 3);    // 0..31

  for (int k0 = 0; k0 < C_DIM; k0 += 64) {
    __syncthreads();
#pragma unroll
    for (int w3 = 0; w3 < 3; ++w3) {
      const unsigned short* W = wbf + (size_t)w3 * (C_DIM * C_DIM);
#pragma unroll
      for (int s = 0; s < 2; ++s) {
        int row = s * 32 + row8;
        int sc = ((lane & 7) ^ (row & 7)) * 8;
        gl_lds16(&W[(size_t)(m0 + row) * C_DIM + k0 + sc],
                 &At[w3][(s * 32 + wave * 8) * 64]);
      }
    }
#pragma unroll
    for (int s = 0; s < 4; ++s) {
      int row = s * 32 + row8;
      int sc = ((lane & 7) ^ (row & 7)) * 8;
      gl_lds16(&hbT[((size_t)b * NPIX + n0 + row) * C_DIM + k0 + sc],
               &Bt[(s * 32 + wave * 8) * 64]);
    }
    __syncthreads();
#pragma unroll
    for (int ks2 = 0; ks2 < 2; ++ks2) {
      bf16x8 bfr[4];
#pragma unroll
      for (int j = 0; j < 4; ++j) {
        int row = wc * 64 + j * 16 + (lane & 15);
        int phys = (ks2 * 4 + (lane >> 4)) ^ (row & 7);
        bfr[j] = *(const bf16x8*)&Bt[row * 64 + phys * 8];
      }
#pragma unroll
      for (int w3 = 0; w3 < 3; ++w3) {
        bf16x8 af[2];
#pragma unroll
        for (int i = 0; i < 2; ++i) {
          int row = wr * 32 + i * 16 + (lane & 15);
          int phys = (ks2 * 4 + (lane >> 4)) ^ (row & 7);
          af[i] = *(const bf16x8*)&At[w3][row * 64 + phys * 8];
        }
#pragma unroll
        for (int i = 0; i < 2; ++i)
#pragma unroll
          for (int j = 0; j < 4; ++j)
            acc[w3][i][j] = __builtin_amdgcn_mfma_f32_16x16x32_bf16(
                af[i], bfr[j], acc[w3][i][j], 0, 0, 0);
      }
    }
  }

#pragma unroll
  for (int w3 = 0; w3 < 3; ++w3) {
    const float* bias = (w3 == 0) ? bq : (w3 == 1) ? bk : bv;
    if (w3 < 2) {
      unsigned short* T = (w3 == 0) ? QT : KT;
      const float qs = (w3 == 0) ? Q_PRESCALE : 1.0f;
#pragma unroll
      for (int i = 0; i < 2; ++i) {
        int o = m0 + wr * 32 + i * 16 + (lane >> 4) * 4;
        float b0 = bias[o + 0], b1 = bias[o + 1], b2 = bias[o + 2], b3 = bias[o + 3];
#pragma unroll
        for (int j = 0; j < 4; ++j) {
          int n = n0 + wc * 64 + j * 16 + (lane & 15);
          ushort4 pk;
          pk.x = f2bf((acc[w3][i][j][0] + b0) * qs);
          pk.y = f2bf((acc[w3][i][j][1] + b1) * qs);
          pk.z = f2bf((acc[w3][i][j][2] + b2) * qs);
          pk.w = f2bf((acc[w3][i][j][3] + b3) * qs);
          *(ushort4*)&T[((size_t)b * NPIX + n) * C_DIM + o] = pk;
        }
      }
    } else {
#pragma unroll
      for (int i = 0; i < 2; ++i) {
        int o = m0 + wr * 32 + i * 16 + (lane >> 4) * 4;
#pragma unroll
        for (int j = 0; j < 4; ++j) {
          int n = n0 + wc * 64 + j * 16 + (lane & 15);
#pragma unroll
          for (int r = 0; r < 4; ++r)
            Vb[((size_t)b * C_DIM + o + r) * NPIX + n] = f2bf(acc[w3][i][j][r] + bias[o + r]);
        }
      }
    }
  }
}

// ---------------- attention v8: r6-v4 structure + VALU rowsum + merged store
// Grid 1024: b=bid&7 (XCD-pinned), h=(bid>>3)&7, qt=(bid>>6)&7, ks=bid>>9.
// 128 q x 512 kpix per block, 4 waves, dbuf-2 (32KB), one barrier per tile.
__global__ __launch_bounds__(256) void k_attn(const unsigned short* __restrict__ QT,
                                              const unsigned short* __restrict__ KT,
                                              const unsigned short* __restrict__ Vb,
                                              unsigned short* __restrict__ Opart,
                                              float* __restrict__ rs) {
  __shared__ unsigned short Ks[2][64 * 64];  // [kpix][c], chunk ^= (row&7)
  __shared__ unsigned short Vs[2][64 * 64];  // [d][kpix], chunk ^= (d&7)
  __shared__ float rs_lds[128];

  const int bid = blockIdx.x;
  const int b = bid & 7, h = (bid >> 3) & 7, qt = (bid >> 6) & 7, ks = bid >> 9;
  const int n0 = qt * 128;
  const int kbase0 = ks * 512;
  const int lane = threadIdx.x & 63, wave = threadIdx.x >> 6;
  const int l31 = lane & 31, hi = lane >> 5;

  bf16x8 qf[4];
  {
    const unsigned short* qbase =
        QT + ((size_t)b * NPIX + n0 + wave * 32 + l31) * C_DIM + h * HDIM + hi * 8;
#pragma unroll
    for (int kk = 0; kk < 4; ++kk) qf[kk] = *(const bf16x8*)(qbase + kk * 16);
  }

  auto stage = [&](int buf, int tile) {
    const int m0 = kbase0 + tile * 64;
#pragma unroll
    for (int it = 0; it < 2; ++it) {
      int rb = it * 32 + wave * 8;
      int row = rb + (lane >> 3);
      int srcc = ((lane & 7) ^ (row & 7)) * 8;
      gl_lds16(&KT[((size_t)b * NPIX + m0 + row) * C_DIM + h * HDIM + srcc],
               &Ks[buf][rb * 64]);
      gl_lds16(&Vb[((size_t)b * C_DIM + h * HDIM + row) * NPIX + m0 + srcc],
               &Vs[buf][rb * 64]);
    }
  };

  f32x16 oacc[2] = {};
  float rs0 = 0.f, rs1 = 0.f;

  stage(0, 0);
  __syncthreads();

  for (int tile = 0; tile < 8; ++tile) {
    const int cur = tile & 1;
    if (tile < 7) stage(cur ^ 1, tile + 1);

#pragma unroll
    for (int kt = 0; kt < 2; ++kt) {
      f32x16 s = {};
#pragma unroll
      for (int kk = 0; kk < 4; ++kk) {
        int row = kt * 32 + l31;
        int phys = (kk * 2 + hi) ^ (row & 7);
        bf16x8 kf = *(const bf16x8*)&Ks[cur][row * 64 + phys * 8];
        s = __builtin_amdgcn_mfma_f32_32x32x16_bf16(kf, qf[kk], s, 0, 0, 0);
      }
      unsigned w[8];
#pragma unroll
      for (int r2 = 0; r2 < 8; ++r2) {
        float e0 = exp2f(s[2 * r2]);
        float e1 = exp2f(s[2 * r2 + 1]);
        rs0 += e0;
        rs1 += e1;
        asm("v_cvt_pk_bf16_f32 %0, %1, %2" : "=v"(w[r2]) : "v"(e0), "v"(e1));
      }
      asm volatile("v_permlane32_swap_b32 %0, %1" : "+v"(w[0]), "+v"(w[2]));
      asm volatile("v_permlane32_swap_b32 %0, %1" : "+v"(w[1]), "+v"(w[3]));
      asm volatile("v_permlane32_swap_b32 %0, %1" : "+v"(w[4]), "+v"(w[6]));
      asm volatile("v_permlane32_swap_b32 %0, %1" : "+v"(w[5]), "+v"(w[7]));
      union U8 { unsigned u[4]; bf16x8 v; };
      U8 pa0, pa1;
      pa0.u[0] = w[0]; pa0.u[1] = w[1]; pa0.u[2] = w[2]; pa0.u[3] = w[3];
      pa1.u[0] = w[4]; pa1.u[1] = w[5]; pa1.u[2] = w[6]; pa1.u[3] = w[7];
#pragma unroll
      for (int dt = 0; dt < 2; ++dt) {
        int d = dt * 32 + l31;
        bf16x8 v0 = *(const bf16x8*)&Vs[cur][d * 64 + (((kt * 4 + hi) ^ (d & 7)) * 8)];
        bf16x8 v1 = *(const bf16x8*)&Vs[cur][d * 64 + (((kt * 4 + 2 + hi) ^ (d & 7)) * 8)];
        oacc[dt] = __builtin_amdgcn_mfma_f32_32x32x16_bf16(pa0.v, v0, oacc[dt], 0, 0, 0);
        oacc[dt] = __builtin_amdgcn_mfma_f32_32x32x16_bf16(pa1.v, v1, oacc[dt], 0, 0, 0);
      }
    }
    __syncthreads();
  }

  float rsq = rs0 + rs1;
  rsq += __shfl_xor(rsq, 32);
  if (hi == 0) rs_lds[wave * 32 + l31] = rsq;
  __syncthreads();

  float inv[16];
#pragma unroll
  for (int r = 0; r < 16; ++r)
    inv[r] = 1.0f / rs_lds[wave * 32 + (r & 3) + 8 * (r >> 2) + 4 * hi];

  __bf16* obase = (__bf16*)(Opart + (size_t)ks * BATCH * NPIX * C_DIM +
                            ((size_t)b * NPIX + n0 + wave * 32) * C_DIM +
                            h * HDIM + l31);
#pragma unroll
  for (int r = 0; r < 16; ++r) {
    int q = (r & 3) + 8 * (r >> 2) + 4 * hi;
#pragma unroll
    for (int dt = 0; dt < 2; ++dt)
      obase[(size_t)q * C_DIM + dt * 32] = (__bf16)(oacc[dt][r] * inv[r]);
  }
  if (hi == 0)
    rs[(((size_t)ks * 8 + b) * 8 + h) * NPIX + n0 + wave * 32 + l31] = rsq;
}

// ---------------- combine split-K partials: AOT = (rsA*OA + rsB*OB)/(rsA+rsB)
__global__ __launch_bounds__(256) void k_comb(const unsigned short* OA,
                                              const unsigned short* OB,
                                              const float* __restrict__ rs,
                                              unsigned short* AOT) {
  int i = blockIdx.x * 256 + threadIdx.x;   // 524288 threads, 8 bf16 each
  int b = i >> 16;
  int rem = i & 65535;
  int n = rem >> 6;
  int c8 = rem & 63;
  int h = c8 >> 3;
  size_t off = ((size_t)b * NPIX + n) * C_DIM + c8 * 8;
  float rsA = rs[(((size_t)0 * 8 + b) * 8 + h) * NPIX + n];
  float rsB = rs[(((size_t)1 * 8 + b) * 8 + h) * NPIX + n];
  float sA = rsA / (rsA + rsB);
  float sB = 1.0f - sA;
  uint4 a = *(const uint4*)(OA + off);
  uint4 bb = *(const uint4*)(OB + off);
  const unsigned* au = (const unsigned*)&a;
  const unsigned* bu = (const unsigned*)&bb;
  uint4 o;
  unsigned* ou = (unsigned*)&o;
#pragma unroll
  for (int j = 0; j < 4; ++j) {
    float a0, a1, b0, b1;
    union { unsigned u; float f; } t;
    t.u = (au[j] & 0xFFFFu) << 16; a0 = t.f;
    t.u = au[j] & 0xFFFF0000u;     a1 = t.f;
    t.u = (bu[j] & 0xFFFFu) << 16; b0 = t.f;
    t.u = bu[j] & 0xFFFF0000u;     b1 = t.f;
    float o0 = sA * a0 + sB * b0;
    float o1 = sA * a1 + sB * b1;
    unsigned pk;
    asm("v_cvt_pk_bf16_f32 %0, %1, %2" : "=v"(pk) : "v"(o0), "v"(o1));
    ou[j] = pk;
  }
  *(uint4*)(AOT + off) = o;
}

// ---------------- proj GEMM + bias + residual (f32 out) ----------------
__global__ __launch_bounds__(256) void k_proj(const unsigned short* __restrict__ Wp,
                                              const float* __restrict__ bp,
                                              const unsigned short* __restrict__ AOT,
                                              const float* __restrict__ x,
                                              float* __restrict__ out) {
  __shared__ unsigned short Atile[128 * 32];
  __shared__ unsigned short Btile[128 * 32];
  const int b = blockIdx.z;
  const int m0 = blockIdx.y * 128, n0 = blockIdx.x * 128;
  const int t = threadIdx.x, wave = t >> 6, lane = t & 63;
  const int wr = wave >> 1, wc = wave & 1;
  f32x4 acc[4][4] = {};
  const int st_row = lane >> 2;
  const int st_col = (((lane & 3) ^ ((lane >> 3) & 3))) * 8;

  for (int k0 = 0; k0 < C_DIM; k0 += 32) {
    __syncthreads();
#pragma unroll
    for (int it = 0; it < 2; ++it) {
      int q = wave + 4 * it;
      int row = q * 16 + st_row;
      gl_lds16(&Wp[(size_t)(m0 + row) * C_DIM + k0 + st_col], &Atile[q * 512]);
      gl_lds16(&AOT[((size_t)b * NPIX + n0 + row) * C_DIM + k0 + st_col], &Btile[q * 512]);
    }
    __syncthreads();
    bf16x8 af[4], bfr[4];
#pragma unroll
    for (int i = 0; i < 4; ++i) {
      int row = wr * 64 + i * 16 + (lane & 15);
      af[i] = *(const bf16x8*)&Atile[row * 32 + (((lane >> 4) ^ ((row >> 1) & 3)) * 8)];
    }
#pragma unroll
    for (int j = 0; j < 4; ++j) {
      int row = wc * 64 + j * 16 + (lane & 15);
      bfr[j] = *(const bf16x8*)&Btile[row * 32 + (((lane >> 4) ^ ((row >> 1) & 3)) * 8)];
    }
#pragma unroll
    for (int i = 0; i < 4; ++i)
#pragma unroll
      for (int j = 0; j < 4; ++j)
        acc[i][j] = __builtin_amdgcn_mfma_f32_16x16x32_bf16(af[i], bfr[j], acc[i][j], 0, 0, 0);
  }

#pragma unroll
  for (int i = 0; i < 4; ++i) {
    int o = m0 + wr * 64 + i * 16 + (lane >> 4) * 4;
    float b0 = bp[o + 0], b1 = bp[o + 1], b2 = bp[o + 2], b3 = bp[o + 3];
#pragma unroll
    for (int j = 0; j < 4; ++j) {
      int n = n0 + wc * 64 + j * 16 + (lane & 15);
      size_t base = ((size_t)b * C_DIM + o) * NPIX + n;
      out[base + 0 * NPIX] = acc[i][j][0] + b0 + x[base + 0 * NPIX];
      out[base + 1 * NPIX] = acc[i][j][1] + b1 + x[base + 1 * NPIX];
      out[base + 2 * NPIX] = acc[i][j][2] + b2 + x[base + 2 * NPIX];
      out[base + 3 * NPIX] = acc[i][j][3] + b3 + x[base + 3 * NPIX];
    }
  }
}

extern "C" void kernel_launch(void* const* d_in, const int* in_sizes, int n_in,
                              void* d_out, int out_size, void* d_ws, size_t ws_size,
                              hipStream_t stream) {
  (void)in_sizes; (void)n_in; (void)out_size; (void)ws_size;
  const float* x     = (const float*)d_in[0];
  const float* gamma = (const float*)d_in[1];
  const float* beta  = (const float*)d_in[2];
  const float* rmean = (const float*)d_in[3];
  const float* rvar  = (const float*)d_in[4];
  const float* wq    = (const float*)d_in[5];
  const float* bq    = (const float*)d_in[6];
  const float* wk    = (const float*)d_in[7];
  const float* bk    = (const float*)d_in[8];
  const float* wv    = (const float*)d_in[9];
  const float* bv    = (const float*)d_in[10];
  const float* wp    = (const float*)d_in[11];
  const float* bp    = (const float*)d_in[12];

  unsigned short* ws  = (unsigned short*)d_ws;
  const size_t WSZ    = (size_t)C_DIM * C_DIM;        // 262144
  const size_t BIG    = (size_t)BATCH * NPIX * C_DIM; // 4194304
  unsigned short* wbf   = ws;                  // 4*WSZ
  unsigned short* hbT   = wbf + 4 * WSZ;
  unsigned short* QT    = hbT + BIG;
  unsigned short* KT    = QT + BIG;
  unsigned short* Vb    = KT + BIG;
  unsigned short* Opart = Vb + BIG;            // 2*BIG
  float*          rs    = (float*)(Opart + 2 * BIG); // 2*8*8*1024 f32 = 512KB
  unsigned short* AOT   = (unsigned short*)(rs + 2 * 8 * 8 * 1024);

  k_prep<<<dim3(512), dim3(256), 0, stream>>>(wq, wk, wv, wp, wbf);
  k_bnT<<<dim3(16, 8, 8), dim3(256), 0, stream>>>(x, gamma, beta, rmean, rvar, hbT);
  k_qkv<<<dim3(8, 8, 8), dim3(256), 0, stream>>>(wbf, bq, bk, bv, hbT, QT, KT, Vb);
  k_attn<<<dim3(1024), dim3(256), 0, stream>>>(QT, KT, Vb, Opart, rs);
  k_comb<<<dim3(2048), dim3(256), 0, stream>>>(Opart, Opart + BIG, rs, AOT);
  k_proj<<<dim3(8, 4, 8), dim3(256), 0, stream>>>(wbf + 3 * WSZ, bp, AOT, x, (float*)d_out);
}

// Round 13
// 172.896 us; speedup vs baseline: 1.3297x; 1.0290x over previous
//
#include <hip/hip_runtime.h>
#include <stdint.h>

#define C_DIM 512
#define NHEADS 8
#define HDIM 64
#define BATCH 8
#define NPIX 1024
// Q pre-scale: (1/sqrt(64)) * log2(e) -> exp becomes bare exp2
#define Q_PRESCALE 0.18033688011112042f

typedef __bf16 bf16x8 __attribute__((ext_vector_type(8)));
typedef float f32x4 __attribute__((ext_vector_type(4)));
typedef float f32x16 __attribute__((ext_vector_type(16)));

__device__ __forceinline__ unsigned short f2bf(float f) {
  union { float f; unsigned u; } v; v.f = f;
  unsigned r = v.u + 0x7fffu + ((v.u >> 16) & 1u);
  return (unsigned short)(r >> 16);
}

__device__ __forceinline__ void gl_lds16(const void* g, void* l) {
  __builtin_amdgcn_global_load_lds(
      (__attribute__((address_space(1))) void*)g,
      (__attribute__((address_space(3))) void*)l,
      16, 0, 0);
}

// ---------------- weights f32 -> bf16 ----------------
__global__ __launch_bounds__(256) void k_prep(const float* __restrict__ wq,
                                              const float* __restrict__ wk,
                                              const float* __restrict__ wv,
                                              const float* __restrict__ wp,
                                              unsigned short* __restrict__ wbf) {
  const int n = C_DIM * C_DIM;
  for (int i = blockIdx.x * blockDim.x + threadIdx.x; i < 4 * n;
       i += gridDim.x * blockDim.x) {
    const float* src = (i < n) ? wq : (i < 2 * n) ? wk : (i < 3 * n) ? wv : wp;
    wbf[i] = f2bf(src[i & (n - 1)]);
  }
}

// ---------------- BN (eval) + transpose: x (B,C,N) f32 -> hbT (B,N,C) bf16 ----
__global__ __launch_bounds__(256) void k_bnT(const float* __restrict__ x,
                                             const float* __restrict__ gamma,
                                             const float* __restrict__ beta,
                                             const float* __restrict__ rmean,
                                             const float* __restrict__ rvar,
                                             unsigned short* __restrict__ hbT) {
  __shared__ unsigned short tile[64][72];
  const int b = blockIdx.z, c0 = blockIdx.y * 64, n0 = blockIdx.x * 64;
  const int t = threadIdx.x;
#pragma unroll
  for (int it = 0; it < 4; ++it) {
    int c = it * 16 + (t >> 4);
    int n = (t & 15) * 4;
    const float4 v = *(const float4*)&x[((size_t)b * C_DIM + c0 + c) * NPIX + n0 + n];
    int cc = c0 + c;
    float inv = gamma[cc] * rsqrtf(rvar[cc] + 1e-5f);
    float add = beta[cc] - rmean[cc] * inv;
    tile[c][n + 0] = f2bf(v.x * inv + add);
    tile[c][n + 1] = f2bf(v.y * inv + add);
    tile[c][n + 2] = f2bf(v.z * inv + add);
    tile[c][n + 3] = f2bf(v.w * inv + add);
  }
  __syncthreads();
#pragma unroll
  for (int it = 0; it < 2; ++it) {
    int n = it * 32 + (t >> 3);
    int cj = (t & 7) * 8;
    unsigned short tmp[8];
#pragma unroll
    for (int u = 0; u < 8; ++u) tmp[u] = tile[cj + u][n];
    uint4 pk;
    pk.x = (unsigned)tmp[0] | ((unsigned)tmp[1] << 16);
    pk.y = (unsigned)tmp[2] | ((unsigned)tmp[3] << 16);
    pk.z = (unsigned)tmp[4] | ((unsigned)tmp[5] << 16);
    pk.w = (unsigned)tmp[6] | ((unsigned)tmp[7] << 16);
    *(uint4*)&hbT[((size_t)b * NPIX + n0 + n) * C_DIM + c0 + cj] = pk;
  }
}

// ---------------- fused QKV GEMM: one block computes Q,K,V for same tile ----
// B (hbT) staged ONCE per block and shared by 3 A-tiles (wq/wk/wv rows).
__global__ __launch_bounds__(256) void k_qkv(const unsigned short* __restrict__ wbf,
                                             const float* __restrict__ bq,
                                             const float* __restrict__ bk,
                                             const float* __restrict__ bv,
                                             const unsigned short* __restrict__ hbT,
                                             unsigned short* __restrict__ QT,
                                             unsigned short* __restrict__ KT,
                                             unsigned short* __restrict__ Vb) {
  __shared__ unsigned short At[3][64 * 64];   // [w3][row][k], chunk ^= (row&7)
  __shared__ unsigned short Bt[128 * 64];     // [n-row][k],  chunk ^= (row&7)
  const int b = blockIdx.z;
  const int m0 = blockIdx.y * 64, n0 = blockIdx.x * 128;
  const int t = threadIdx.x, wave = t >> 6, lane = t & 63;
  const int wr = wave >> 1, wc = wave & 1;
  f32x4 acc[3][2][4] = {};

  const int row8 = wave * 8 + (lane >> 3);    // 0..31

  for (int k0 = 0; k0 < C_DIM; k0 += 64) {
    __syncthreads();
#pragma unroll
    for (int w3 = 0; w3 < 3; ++w3) {
      const unsigned short* W = wbf + (size_t)w3 * (C_DIM * C_DIM);
#pragma unroll
      for (int s = 0; s < 2; ++s) {
        int row = s * 32 + row8;
        int sc = ((lane & 7) ^ (row & 7)) * 8;
        gl_lds16(&W[(size_t)(m0 + row) * C_DIM + k0 + sc],
                 &At[w3][(s * 32 + wave * 8) * 64]);
      }
    }
#pragma unroll
    for (int s = 0; s < 4; ++s) {
      int row = s * 32 + row8;
      int sc = ((lane & 7) ^ (row & 7)) * 8;
      gl_lds16(&hbT[((size_t)b * NPIX + n0 + row) * C_DIM + k0 + sc],
               &Bt[(s * 32 + wave * 8) * 64]);
    }
    __syncthreads();
#pragma unroll
    for (int ks2 = 0; ks2 < 2; ++ks2) {
      bf16x8 bfr[4];
#pragma unroll
      for (int j = 0; j < 4; ++j) {
        int row = wc * 64 + j * 16 + (lane & 15);
        int phys = (ks2 * 4 + (lane >> 4)) ^ (row & 7);
        bfr[j] = *(const bf16x8*)&Bt[row * 64 + phys * 8];
      }
#pragma unroll
      for (int w3 = 0; w3 < 3; ++w3) {
        bf16x8 af[2];
#pragma unroll
        for (int i = 0; i < 2; ++i) {
          int row = wr * 32 + i * 16 + (lane & 15);
          int phys = (ks2 * 4 + (lane >> 4)) ^ (row & 7);
          af[i] = *(const bf16x8*)&At[w3][row * 64 + phys * 8];
        }
#pragma unroll
        for (int i = 0; i < 2; ++i)
#pragma unroll
          for (int j = 0; j < 4; ++j)
            acc[w3][i][j] = __builtin_amdgcn_mfma_f32_16x16x32_bf16(
                af[i], bfr[j], acc[w3][i][j], 0, 0, 0);
      }
    }
  }

#pragma unroll
  for (int w3 = 0; w3 < 3; ++w3) {
    const float* bias = (w3 == 0) ? bq : (w3 == 1) ? bk : bv;
    if (w3 < 2) {
      unsigned short* T = (w3 == 0) ? QT : KT;
      const float qs = (w3 == 0) ? Q_PRESCALE : 1.0f;
#pragma unroll
      for (int i = 0; i < 2; ++i) {
        int o = m0 + wr * 32 + i * 16 + (lane >> 4) * 4;
        float b0 = bias[o + 0], b1 = bias[o + 1], b2 = bias[o + 2], b3 = bias[o + 3];
#pragma unroll
        for (int j = 0; j < 4; ++j) {
          int n = n0 + wc * 64 + j * 16 + (lane & 15);
          ushort4 pk;
          pk.x = f2bf((acc[w3][i][j][0] + b0) * qs);
          pk.y = f2bf((acc[w3][i][j][1] + b1) * qs);
          pk.z = f2bf((acc[w3][i][j][2] + b2) * qs);
          pk.w = f2bf((acc[w3][i][j][3] + b3) * qs);
          *(ushort4*)&T[((size_t)b * NPIX + n) * C_DIM + o] = pk;
        }
      }
    } else {
#pragma unroll
      for (int i = 0; i < 2; ++i) {
        int o = m0 + wr * 32 + i * 16 + (lane >> 4) * 4;
#pragma unroll
        for (int j = 0; j < 4; ++j) {
          int n = n0 + wc * 64 + j * 16 + (lane & 15);
#pragma unroll
          for (int r = 0; r < 4; ++r)
            Vb[((size_t)b * C_DIM + o + r) * NPIX + n] = f2bf(acc[w3][i][j][r] + bias[o + r]);
        }
      }
    }
  }
}

// ---------------- attention v9: exact r6-v4 body + asm v_exp_f32 -----------
// Grid 1024: b=bid&7 (XCD-pinned), h=(bid>>3)&7, qt=(bid>>6)&7, ks=bid>>9.
// 128 q x 512 kpix, 4 waves, dbuf-2 (32KB). Rowsum via ones-MFMA (idle matrix
// pipe, same C/D layout as oacc -> same-lane normalize, no extra barrier).
// exp2f replaced by bare v_exp_f32 (ocml exp2 carries subnormal fixup VALU).
__global__ __launch_bounds__(256) void k_attn(const unsigned short* __restrict__ QT,
                                              const unsigned short* __restrict__ KT,
                                              const unsigned short* __restrict__ Vb,
                                              unsigned short* __restrict__ Opart,
                                              float* __restrict__ rs) {
  __shared__ unsigned short Ks[2][64 * 64];  // [kpix][c], chunk ^= (row&7)
  __shared__ unsigned short Vs[2][64 * 64];  // [d][kpix], chunk ^= (d&7)

  const int bid = blockIdx.x;
  const int b = bid & 7, h = (bid >> 3) & 7, qt = (bid >> 6) & 7, ks = bid >> 9;
  const int n0 = qt * 128;
  const int kbase0 = ks * 512;
  const int lane = threadIdx.x & 63, wave = threadIdx.x >> 6;
  const int l31 = lane & 31, hi = lane >> 5;

  bf16x8 qf[4];
  {
    const unsigned short* qbase =
        QT + ((size_t)b * NPIX + n0 + wave * 32 + l31) * C_DIM + h * HDIM + hi * 8;
#pragma unroll
    for (int kk = 0; kk < 4; ++kk) qf[kk] = *(const bf16x8*)(qbase + kk * 16);
  }

  union { unsigned u[4]; bf16x8 v; } ones;
  ones.u[0] = 0x3F803F80u; ones.u[1] = 0x3F803F80u;
  ones.u[2] = 0x3F803F80u; ones.u[3] = 0x3F803F80u;

  auto stage = [&](int buf, int tile) {
    const int m0 = kbase0 + tile * 64;
#pragma unroll
    for (int it = 0; it < 2; ++it) {
      int rb = it * 32 + wave * 8;
      int row = rb + (lane >> 3);
      int srcc = ((lane & 7) ^ (row & 7)) * 8;
      gl_lds16(&KT[((size_t)b * NPIX + m0 + row) * C_DIM + h * HDIM + srcc],
               &Ks[buf][rb * 64]);
      gl_lds16(&Vb[((size_t)b * C_DIM + h * HDIM + row) * NPIX + m0 + srcc],
               &Vs[buf][rb * 64]);
    }
  };

  f32x16 oacc[2] = {};
  f32x16 rsacc = {};

  stage(0, 0);
  __syncthreads();

  for (int tile = 0; tile < 8; ++tile) {
    const int cur = tile & 1;
    if (tile < 7) stage(cur ^ 1, tile + 1);

#pragma unroll
    for (int kt = 0; kt < 2; ++kt) {
      // S^T 32x32: A = K [32 kpix x 16 c], B = Q. Lane holds col q=l31.
      f32x16 s = {};
#pragma unroll
      for (int kk = 0; kk < 4; ++kk) {
        int row = kt * 32 + l31;
        int phys = (kk * 2 + hi) ^ (row & 7);
        bf16x8 kf = *(const bf16x8*)&Ks[cur][row * 64 + phys * 8];
        s = __builtin_amdgcn_mfma_f32_32x32x16_bf16(kf, qf[kk], s, 0, 0, 0);
      }
      // P = 2^s via bare v_exp_f32 (clip-free); pack bf16 in-register.
      unsigned w[8];
#pragma unroll
      for (int r2 = 0; r2 < 8; ++r2) {
        float e0, e1;
        asm("v_exp_f32 %0, %1" : "=v"(e0) : "v"(s[2 * r2]));
        asm("v_exp_f32 %0, %1" : "=v"(e1) : "v"(s[2 * r2 + 1]));
        asm("v_cvt_pk_bf16_f32 %0, %1, %2" : "=v"(w[r2]) : "v"(e0), "v"(e1));
      }
      asm volatile("v_permlane32_swap_b32 %0, %1" : "+v"(w[0]), "+v"(w[2]));
      asm volatile("v_permlane32_swap_b32 %0, %1" : "+v"(w[1]), "+v"(w[3]));
      asm volatile("v_permlane32_swap_b32 %0, %1" : "+v"(w[4]), "+v"(w[6]));
      asm volatile("v_permlane32_swap_b32 %0, %1" : "+v"(w[5]), "+v"(w[7]));
      union U8 { unsigned u[4]; bf16x8 v; };
      U8 pa0, pa1;
      pa0.u[0] = w[0]; pa0.u[1] = w[1]; pa0.u[2] = w[2]; pa0.u[3] = w[3];
      pa1.u[0] = w[4]; pa1.u[1] = w[5]; pa1.u[2] = w[6]; pa1.u[3] = w[7];
      // Rowsum on the idle matrix pipe; same C/D layout as oacc.
      rsacc = __builtin_amdgcn_mfma_f32_32x32x16_bf16(pa0.v, ones.v, rsacc, 0, 0, 0);
      rsacc = __builtin_amdgcn_mfma_f32_32x32x16_bf16(pa1.v, ones.v, rsacc, 0, 0, 0);
      // PV: O[q][d] += P[q][k] * V[d][k]
#pragma unroll
      for (int dt = 0; dt < 2; ++dt) {
        int d = dt * 32 + l31;
        bf16x8 v0 = *(const bf16x8*)&Vs[cur][d * 64 + (((kt * 4 + hi) ^ (d & 7)) * 8)];
        bf16x8 v1 = *(const bf16x8*)&Vs[cur][d * 64 + (((kt * 4 + 2 + hi) ^ (d & 7)) * 8)];
        oacc[dt] = __builtin_amdgcn_mfma_f32_32x32x16_bf16(pa0.v, v0, oacc[dt], 0, 0, 0);
        oacc[dt] = __builtin_amdgcn_mfma_f32_32x32x16_bf16(pa1.v, v1, oacc[dt], 0, 0, 0);
      }
    }
    __syncthreads();
  }

  // Normalize partial (same-lane: oacc/rsacc share C/D layout) and store.
  float inv[16];
#pragma unroll
  for (int r = 0; r < 16; ++r) inv[r] = 1.0f / rsacc[r];

  __bf16* obase = (__bf16*)(Opart + (size_t)ks * BATCH * NPIX * C_DIM +
                            ((size_t)b * NPIX + n0 + wave * 32) * C_DIM +
                            h * HDIM + l31);
#pragma unroll
  for (int dt = 0; dt < 2; ++dt)
#pragma unroll
    for (int r = 0; r < 16; ++r) {
      int q = (r & 3) + 8 * (r >> 2) + 4 * hi;
      obase[(size_t)q * C_DIM + dt * 32] = (__bf16)(oacc[dt][r] * inv[r]);
    }
  if (l31 == 0) {
    float* rbase = rs + (((size_t)ks * 8 + b) * 8 + h) * NPIX + n0 + wave * 32;
#pragma unroll
    for (int r = 0; r < 16; ++r)
      rbase[(r & 3) + 8 * (r >> 2) + 4 * hi] = rsacc[r];
  }
}

// ---------------- combine split-K partials: AOT = (rsA*OA + rsB*OB)/(rsA+rsB)
__global__ __launch_bounds__(256) void k_comb(const unsigned short* OA,
                                              const unsigned short* OB,
                                              const float* __restrict__ rs,
                                              unsigned short* AOT) {
  int i = blockIdx.x * 256 + threadIdx.x;   // 524288 threads, 8 bf16 each
  int b = i >> 16;
  int rem = i & 65535;
  int n = rem >> 6;
  int c8 = rem & 63;
  int h = c8 >> 3;
  size_t off = ((size_t)b * NPIX + n) * C_DIM + c8 * 8;
  float rsA = rs[(((size_t)0 * 8 + b) * 8 + h) * NPIX + n];
  float rsB = rs[(((size_t)1 * 8 + b) * 8 + h) * NPIX + n];
  float sA = rsA / (rsA + rsB);
  float sB = 1.0f - sA;
  uint4 a = *(const uint4*)(OA + off);
  uint4 bb = *(const uint4*)(OB + off);
  const unsigned* au = (const unsigned*)&a;
  const unsigned* bu = (const unsigned*)&bb;
  uint4 o;
  unsigned* ou = (unsigned*)&o;
#pragma unroll
  for (int j = 0; j < 4; ++j) {
    float a0, a1, b0, b1;
    union { unsigned u; float f; } t;
    t.u = (au[j] & 0xFFFFu) << 16; a0 = t.f;
    t.u = au[j] & 0xFFFF0000u;     a1 = t.f;
    t.u = (bu[j] & 0xFFFFu) << 16; b0 = t.f;
    t.u = bu[j] & 0xFFFF0000u;     b1 = t.f;
    float o0 = sA * a0 + sB * b0;
    float o1 = sA * a1 + sB * b1;
    unsigned pk;
    asm("v_cvt_pk_bf16_f32 %0, %1, %2" : "=v"(pk) : "v"(o0), "v"(o1));
    ou[j] = pk;
  }
  *(uint4*)(AOT + off) = o;
}

// ---------------- proj GEMM + bias + residual (f32 out) ----------------
__global__ __launch_bounds__(256) void k_proj(const unsigned short* __restrict__ Wp,
                                              const float* __restrict__ bp,
                                              const unsigned short* __restrict__ AOT,
                                              const float* __restrict__ x,
                                              float* __restrict__ out) {
  __shared__ unsigned short Atile[128 * 32];
  __shared__ unsigned short Btile[128 * 32];
  const int b = blockIdx.z;
  const int m0 = blockIdx.y * 128, n0 = blockIdx.x * 128;
  const int t = threadIdx.x, wave = t >> 6, lane = t & 63;
  const int wr = wave >> 1, wc = wave & 1;
  f32x4 acc[4][4] = {};
  const int st_row = lane >> 2;
  const int st_col = (((lane & 3) ^ ((lane >> 3) & 3))) * 8;

  for (int k0 = 0; k0 < C_DIM; k0 += 32) {
    __syncthreads();
#pragma unroll
    for (int it = 0; it < 2; ++it) {
      int q = wave + 4 * it;
      int row = q * 16 + st_row;
      gl_lds16(&Wp[(size_t)(m0 + row) * C_DIM + k0 + st_col], &Atile[q * 512]);
      gl_lds16(&AOT[((size_t)b * NPIX + n0 + row) * C_DIM + k0 + st_col], &Btile[q * 512]);
    }
    __syncthreads();
    bf16x8 af[4], bfr[4];
#pragma unroll
    for (int i = 0; i < 4; ++i) {
      int row = wr * 64 + i * 16 + (lane & 15);
      af[i] = *(const bf16x8*)&Atile[row * 32 + (((lane >> 4) ^ ((row >> 1) & 3)) * 8)];
    }
#pragma unroll
    for (int j = 0; j < 4; ++j) {
      int row = wc * 64 + j * 16 + (lane & 15);
      bfr[j] = *(const bf16x8*)&Btile[row * 32 + (((lane >> 4) ^ ((row >> 1) & 3)) * 8)];
    }
#pragma unroll
    for (int i = 0; i < 4; ++i)
#pragma unroll
      for (int j = 0; j < 4; ++j)
        acc[i][j] = __builtin_amdgcn_mfma_f32_16x16x32_bf16(af[i], bfr[j], acc[i][j], 0, 0, 0);
  }

#pragma unroll
  for (int i = 0; i < 4; ++i) {
    int o = m0 + wr * 64 + i * 16 + (lane >> 4) * 4;
    float b0 = bp[o + 0], b1 = bp[o + 1], b2 = bp[o + 2], b3 = bp[o + 3];
#pragma unroll
    for (int j = 0; j < 4; ++j) {
      int n = n0 + wc * 64 + j * 16 + (lane & 15);
      size_t base = ((size_t)b * C_DIM + o) * NPIX + n;
      out[base + 0 * NPIX] = acc[i][j][0] + b0 + x[base + 0 * NPIX];
      out[base + 1 * NPIX] = acc[i][j][1] + b1 + x[base + 1 * NPIX];
      out[base + 2 * NPIX] = acc[i][j][2] + b2 + x[base + 2 * NPIX];
      out[base + 3 * NPIX] = acc[i][j][3] + b3 + x[base + 3 * NPIX];
    }
  }
}

extern "C" void kernel_launch(void* const* d_in, const int* in_sizes, int n_in,
                              void* d_out, int out_size, void* d_ws, size_t ws_size,
                              hipStream_t stream) {
  (void)in_sizes; (void)n_in; (void)out_size; (void)ws_size;
  const float* x     = (const float*)d_in[0];
  const float* gamma = (const float*)d_in[1];
  const float* beta  = (const float*)d_in[2];
  const float* rmean = (const float*)d_in[3];
  const float* rvar  = (const float*)d_in[4];
  const float* wq    = (const float*)d_in[5];
  const float* bq    = (const float*)d_in[6];
  const float* wk    = (const float*)d_in[7];
  const float* bk    = (const float*)d_in[8];
  const float* wv    = (const float*)d_in[9];
  const float* bv    = (const float*)d_in[10];
  const float* wp    = (const float*)d_in[11];
  const float* bp    = (const float*)d_in[12];

  unsigned short* ws  = (unsigned short*)d_ws;
  const size_t WSZ    = (size_t)C_DIM * C_DIM;        // 262144
  const size_t BIG    = (size_t)BATCH * NPIX * C_DIM; // 4194304
  unsigned short* wbf   = ws;                  // 4*WSZ
  unsigned short* hbT   = wbf + 4 * WSZ;
  unsigned short* QT    = hbT + BIG;
  unsigned short* KT    = QT + BIG;
  unsigned short* Vb    = KT + BIG;
  unsigned short* Opart = Vb + BIG;            // 2*BIG
  float*          rs    = (float*)(Opart + 2 * BIG); // 2*8*8*1024 f32 = 512KB
  unsigned short* AOT   = (unsigned short*)(rs + 2 * 8 * 8 * 1024);

  k_prep<<<dim3(512), dim3(256), 0, stream>>>(wq, wk, wv, wp, wbf);
  k_bnT<<<dim3(16, 8, 8), dim3(256), 0, stream>>>(x, gamma, beta, rmean, rvar, hbT);
  k_qkv<<<dim3(8, 8, 8), dim3(256), 0, stream>>>(wbf, bq, bk, bv, hbT, QT, KT, Vb);
  k_attn<<<dim3(1024), dim3(256), 0, stream>>>(QT, KT, Vb, Opart, rs);
  k_comb<<<dim3(2048), dim3(256), 0, stream>>>(Opart, Opart + BIG, rs, AOT);
  k_proj<<<dim3(8, 4, 8), dim3(256), 0, stream>>>(wbf + 3 * WSZ, bp, AOT, x, (float*)d_out);
}